// Round 2
// baseline (22189.503 us; speedup 1.0000x reference)
//
#include <hip/hip_runtime.h>
#include <hip/hip_bf16.h>

typedef __hip_bfloat16 bf16;

// Problem constants
#define BB   128
#define TT   256
#define CC   384
#define HH   4
#define DH   64
#define LL   6
#define VV   65
#define FFD  1536
#define BT   (BB * TT)   // 32768
#define FCH  4096        // FF row-chunk

__device__ __forceinline__ float b2f(bf16 h) { return __bfloat162float(h); }
__device__ __forceinline__ bf16  f2b(float f) { return __float2bfloat16(f); }

// ---------------------------------------------------------------------------
// Detect input dtype: fp32 (flag=1) vs bf16 (flag=0), by examining tok_emb
// bit patterns. bf16 N(0,0.02) never has exponent >= 130 (|v|>=8); fp32 read
// as uint16 pairs has garbage low-halves with uniform exponents (~50% >= 130).
// ---------------------------------------------------------------------------
__global__ __launch_bounds__(256) void detect_kernel(const unsigned short* __restrict__ tok,
                                                     int* __restrict__ flag)
{
  __shared__ int cnt;
  if (threadIdx.x == 0) cnt = 0;
  __syncthreads();
  int c = 0;
  for (int i = threadIdx.x; i < 512; i += 256) {
    int e = (tok[i] >> 7) & 0xFF;
    if (e >= 130) c++;
  }
  atomicAdd(&cnt, c);
  __syncthreads();
  if (threadIdx.x == 0) flag[0] = (cnt > 16) ? 1 : 0;
}

// Canonicalize a float tensor (fp32 or bf16 per flag) into bf16.
__global__ __launch_bounds__(256) void convert_kernel(const void* __restrict__ src,
                                                      bf16* __restrict__ dst, int n,
                                                      const int* __restrict__ flag)
{
  int i = blockIdx.x * 256 + threadIdx.x;
  if (i >= n) return;
  float v = flag[0] ? ((const float*)src)[i] : b2f(((const bf16*)src)[i]);
  dst[i] = f2b(v);
}

// ---------------------------------------------------------------------------
// Embedding: x[bt, c] = tok_emb[idx[bt], c] + pos_emb[bt % T, c]   (fp32 out)
// ---------------------------------------------------------------------------
__global__ __launch_bounds__(CC) void embed_kernel(
    const int* __restrict__ idx, const bf16* __restrict__ tok,
    const bf16* __restrict__ pos, float* __restrict__ x)
{
  int bt = blockIdx.x;
  int c  = threadIdx.x;
  int tok_id = idx[bt];
  int t = bt & (TT - 1);
  x[(size_t)bt * CC + c] = b2f(tok[(size_t)tok_id * CC + c]) + b2f(pos[(size_t)t * CC + c]);
}

// ---------------------------------------------------------------------------
// Repack Wq/Wk/Wv from [L,H,C,HS] (fp32 or bf16 per flag) to bf16 [L, C, H*HS]
// ---------------------------------------------------------------------------
__global__ __launch_bounds__(256) void repack_qkv(const void* __restrict__ w,
                                                  bf16* __restrict__ out, int total,
                                                  const int* __restrict__ flag)
{
  int i = blockIdx.x * 256 + threadIdx.x;
  if (i >= total) return;
  int l   = i / (CC * 256);
  int rem = i - l * (CC * 256);
  int c = rem >> 8;
  int n = rem & 255;
  int h = n >> 6;
  int d = n & 63;
  size_t si = (((size_t)l * HH + h) * CC + c) * DH + d;
  float v = flag[0] ? ((const float*)w)[si] : b2f(((const bf16*)w)[si]);
  out[i] = f2b(v);
}

// ---------------------------------------------------------------------------
// LayerNorm: fp32 x row -> bf16 xn row. One wave per row (C=384 -> 6/lane).
// ---------------------------------------------------------------------------
__global__ __launch_bounds__(256) void ln_kernel(
    const float* __restrict__ x, bf16* __restrict__ xn,
    const bf16* __restrict__ g, const bf16* __restrict__ b)
{
  int lane = threadIdx.x & 63;
  int wid  = threadIdx.x >> 6;
  int r = blockIdx.x * 4 + wid;
  const float* xr = x + (size_t)r * CC;
  float vals[6];
  float s = 0.f, ss = 0.f;
#pragma unroll
  for (int i = 0; i < 6; ++i) {
    float v = xr[lane + i * 64];
    vals[i] = v; s += v; ss += v * v;
  }
#pragma unroll
  for (int off = 32; off; off >>= 1) {
    s  += __shfl_xor(s, off, 64);
    ss += __shfl_xor(ss, off, 64);
  }
  float mu   = s * (1.f / CC);
  float var  = ss * (1.f / CC) - mu * mu;
  float rstd = rsqrtf(var + 1e-5f);
  bf16* xo = xn + (size_t)r * CC;
#pragma unroll
  for (int i = 0; i < 6; ++i) {
    int c = lane + i * 64;
    xo[c] = f2b((vals[i] - mu) * rstd * b2f(g[c]) + b2f(b[c]));
  }
}

// ---------------------------------------------------------------------------
// Generic tiled GEMM: C = A[M,K](bf16) * B[K,N](bf16) (+bias) with epilogues.
// 64x64 tile, 256 threads, 4x4 microtile, fp32 accumulate, K%32==0, N%64==0.
// ---------------------------------------------------------------------------
enum { OUT_BF16 = 0, OUT_QKV = 1, OUT_RES = 2 };

template<int MODE, bool RELU>
__global__ __launch_bounds__(256) void gemm_kernel(
    const bf16* __restrict__ A, const bf16* __restrict__ Bm,
    const bf16* __restrict__ bias, void* __restrict__ out,
    int M, int N, int K)
{
  __shared__ float As[64][33];
  __shared__ float Bs[32][65];
  int tid = threadIdx.x;
  int m0 = blockIdx.y * 64;
  int n0 = blockIdx.x * 64;
  int tx = tid & 15, ty = tid >> 4;
  float acc[4][4] = {};
  int arow = tid >> 2, acg = (tid & 3) * 8;  // A: 64 rows x 32 k, 8 elems/thread
  int brow = tid >> 3, bcg = (tid & 7) * 8;  // B: 32 k x 64 cols, 8 elems/thread

  for (int k0 = 0; k0 < K; k0 += 32) {
    int4 ua = *reinterpret_cast<const int4*>(A  + (size_t)(m0 + arow) * K + k0 + acg);
    int4 ub = *reinterpret_cast<const int4*>(Bm + (size_t)(k0 + brow) * N + n0 + bcg);
    unsigned* pa = reinterpret_cast<unsigned*>(&ua);
    unsigned* pb = reinterpret_cast<unsigned*>(&ub);
#pragma unroll
    for (int j = 0; j < 4; ++j) {
      As[arow][acg + 2*j]     = __uint_as_float(pa[j] << 16);
      As[arow][acg + 2*j + 1] = __uint_as_float(pa[j] & 0xffff0000u);
      Bs[brow][bcg + 2*j]     = __uint_as_float(pb[j] << 16);
      Bs[brow][bcg + 2*j + 1] = __uint_as_float(pb[j] & 0xffff0000u);
    }
    __syncthreads();
#pragma unroll
    for (int kkk = 0; kkk < 32; ++kkk) {
      float av[4], bv[4];
#pragma unroll
      for (int i = 0; i < 4; ++i) av[i] = As[ty * 4 + i][kkk];
#pragma unroll
      for (int j = 0; j < 4; ++j) bv[j] = Bs[kkk][tx * 4 + j];
#pragma unroll
      for (int i = 0; i < 4; ++i)
#pragma unroll
        for (int j = 0; j < 4; ++j) acc[i][j] += av[i] * bv[j];
    }
    __syncthreads();
  }

#pragma unroll
  for (int i = 0; i < 4; ++i) {
    int m = m0 + ty * 4 + i;
#pragma unroll
    for (int j = 0; j < 4; ++j) {
      int n = n0 + tx * 4 + j;
      float r = acc[i][j];
      if (MODE == OUT_BF16) {
        if (bias) r += b2f(bias[n]);
        if (RELU) r = fmaxf(r, 0.f);
        reinterpret_cast<bf16*>(out)[(size_t)m * N + n] = f2b(r);
      } else if (MODE == OUT_RES) {
        r += b2f(bias[n]);
        reinterpret_cast<float*>(out)[(size_t)m * N + n] += r;   // residual add (fp32)
      } else {  // OUT_QKV: scatter [BT, H*HS] -> [B,H,T,HS]
        int bidx = m >> 8, trow = m & 255;
        int h = n >> 6,    d    = n & 63;
        reinterpret_cast<bf16*>(out)[(((size_t)bidx * HH + h) * TT + trow) * DH + d] = f2b(r);
      }
    }
  }
}

// ---------------------------------------------------------------------------
// Fused causal attention: one block per (b,h,t). Scores+softmax+PV in LDS.
// q,k,v: [B,H,T,HS] bf16.  att out: [B,T,H*HS] bf16.
// ---------------------------------------------------------------------------
__global__ __launch_bounds__(256) void attn_kernel(
    const bf16* __restrict__ q, const bf16* __restrict__ kptr,
    const bf16* __restrict__ vptr, bf16* __restrict__ att)
{
  int t   = blockIdx.x;
  int bh  = blockIdx.y;            // b*H + h
  int tid = threadIdx.x;
  int lane = tid & 63, wid = tid >> 6;
  __shared__ float qs[DH];
  __shared__ float wei[TT];
  __shared__ float wmax[4], wsum[4];
  __shared__ float pv[4][DH];

  const bf16* qrow = q + ((size_t)bh * TT + t) * DH;
  if (tid < DH) qs[tid] = b2f(qrow[tid]);
  __syncthreads();

  int s = tid;                     // blockDim == T == 256
  float sc = -INFINITY;
  if (s <= t) {
    const bf16* krow = kptr + ((size_t)bh * TT + s) * DH;
    float a = 0.f;
#pragma unroll
    for (int d = 0; d < DH; d += 4) {
      ushort4 u = *reinterpret_cast<const ushort4*>(krow + d);
      a += qs[d]     * __uint_as_float((unsigned)u.x << 16);
      a += qs[d + 1] * __uint_as_float((unsigned)u.y << 16);
      a += qs[d + 2] * __uint_as_float((unsigned)u.z << 16);
      a += qs[d + 3] * __uint_as_float((unsigned)u.w << 16);
    }
    sc = a * 0.125f;               // HS^-0.5
  }
  float m = sc;
#pragma unroll
  for (int off = 32; off; off >>= 1) m = fmaxf(m, __shfl_xor(m, off, 64));
  if (lane == 0) wmax[wid] = m;
  __syncthreads();
  float mx = fmaxf(fmaxf(wmax[0], wmax[1]), fmaxf(wmax[2], wmax[3]));
  float e = (s <= t) ? __expf(sc - mx) : 0.f;
  wei[s] = e;
  float sum = e;
#pragma unroll
  for (int off = 32; off; off >>= 1) sum += __shfl_xor(sum, off, 64);
  if (lane == 0) wsum[wid] = sum;
  __syncthreads();
  float denom = wsum[0] + wsum[1] + wsum[2] + wsum[3];

  // PV: thread = (quarter of s-range, d)
  int d  = tid & 63, qd = tid >> 6;
  float a = 0.f;
  int s0 = qd * 64, s1 = min(s0 + 64, t + 1);
  for (int s2 = s0; s2 < s1; ++s2)
    a += wei[s2] * b2f(vptr[((size_t)bh * TT + s2) * DH + d]);
  pv[qd][d] = a;
  __syncthreads();
  if (tid < DH) {
    float o = (pv[0][tid] + pv[1][tid] + pv[2][tid] + pv[3][tid]) / denom;
    int b = bh >> 2, h = bh & 3;   // H = 4
    att[(((size_t)b * TT + t) * HH + h) * DH + tid] = f2b(o);
  }
}

// ---------------------------------------------------------------------------
// LM head + log-softmax + loss. One wave per row; lane n covers col n,
// lane 0 additionally covers col 64 (V=65). Logits -> d_out (dtype per flag).
// ---------------------------------------------------------------------------
__global__ __launch_bounds__(64) void lmhead_kernel(
    const bf16* __restrict__ xn, const bf16* __restrict__ Wlm,
    const bf16* __restrict__ blm, const int* __restrict__ targets,
    void* __restrict__ out, float* __restrict__ loss,
    const int* __restrict__ flag)
{
  int r = blockIdx.x;
  int lane = threadIdx.x;
  __shared__ float xs[CC];
#pragma unroll
  for (int i = 0; i < CC / 64; ++i) xs[lane + i * 64] = b2f(xn[(size_t)r * CC + lane + i * 64]);
  __syncthreads();
  float a0 = 0.f, a1 = 0.f;
  for (int c = 0; c < CC; ++c) {
    float xv = xs[c];
    a0 += xv * b2f(Wlm[(size_t)c * VV + lane]);
    if (lane == 0) a1 += xv * b2f(Wlm[(size_t)c * VV + 64]);
  }
  a0 += b2f(blm[lane]);
  if (lane == 0) a1 += b2f(blm[64]);
  if (flag[0]) {
    float* o = (float*)out;
    o[(size_t)r * VV + lane] = a0;
    if (lane == 0) o[(size_t)r * VV + 64] = a1;
  } else {
    bf16* o = (bf16*)out;
    o[(size_t)r * VV + lane] = f2b(a0);
    if (lane == 0) o[(size_t)r * VV + 64] = f2b(a1);
  }

  float m = (lane == 0) ? fmaxf(a0, a1) : a0;
#pragma unroll
  for (int off = 32; off; off >>= 1) m = fmaxf(m, __shfl_xor(m, off, 64));
  float e = __expf(a0 - m) + ((lane == 0) ? __expf(a1 - m) : 0.f);
#pragma unroll
  for (int off = 32; off; off >>= 1) e += __shfl_xor(e, off, 64);
  float logZ = m + logf(e);
  int tgt = targets[r];
  float contrib = (lane == tgt) ? (a0 - logZ) : 0.f;
  if (lane == 0 && tgt == 64) contrib = a1 - logZ;
#pragma unroll
  for (int off = 32; off; off >>= 1) contrib += __shfl_xor(contrib, off, 64);
  if (lane == 0) atomicAdd(loss, -contrib);
}

__global__ void finalize_kernel(const float* __restrict__ loss, void* __restrict__ out,
                                const int* __restrict__ flag)
{
  float v = loss[0] * (1.f / BT);
  if (flag[0]) ((float*)out)[(size_t)BT * VV] = v;
  else         ((bf16*)out)[(size_t)BT * VV]  = f2b(v);
}

// ---------------------------------------------------------------------------
extern "C" void kernel_launch(void* const* d_in, const int* in_sizes, int n_in,
                              void* d_out, int out_size, void* d_ws, size_t ws_size,
                              hipStream_t stream)
{
  const int* idx     = (const int*)d_in[0];
  const int* targets = (const int*)d_in[1];
  const void* tok  = d_in[2];
  const void* pos  = d_in[3];
  const void* Wq   = d_in[4];
  const void* Wk   = d_in[5];
  const void* Wv   = d_in[6];
  const void* Wo   = d_in[7];
  const void* bo   = d_in[8];
  const void* W1   = d_in[9];
  const void* b1   = d_in[10];
  const void* W2   = d_in[11];
  const void* b2   = d_in[12];
  const void* ln1g = d_in[13];
  const void* ln1b = d_in[14];
  const void* ln2g = d_in[15];
  const void* ln2b = d_in[16];
  const void* lnfg = d_in[17];
  const void* lnfb = d_in[18];
  const void* Wlm  = d_in[19];
  const void* blm  = d_in[20];

  char* ws = (char*)d_ws;
  size_t off = 0;
  auto alloc = [&](size_t bytes) { void* p = ws + off; off += (bytes + 255) & ~(size_t)255; return p; };

  float* x   = (float*)alloc((size_t)BT * CC * 4);            // 50.3 MB
  bf16*  xn  = (bf16*)alloc((size_t)BT * CC * 2);             // 25.2 MB
  bf16*  qb  = (bf16*)alloc((size_t)BB * HH * TT * DH * 2);   // 16.8 MB x3
  bf16*  kb  = (bf16*)alloc((size_t)BB * HH * TT * DH * 2);
  bf16*  vb  = (bf16*)alloc((size_t)BB * HH * TT * DH * 2);
  bf16*  att = (bf16*)alloc((size_t)BT * 256 * 2);            // 16.8 MB
  bf16*  ff1 = (bf16*)alloc((size_t)FCH * FFD * 2);           // 12.6 MB
  // canonical bf16 weight pool
  bf16* c_tok = (bf16*)alloc((size_t)VV * CC * 2);
  bf16* c_pos = (bf16*)alloc((size_t)TT * CC * 2);
  bf16* c_Wo  = (bf16*)alloc((size_t)LL * 256 * CC * 2);
  bf16* c_bo  = (bf16*)alloc((size_t)LL * CC * 2);
  bf16* c_W1  = (bf16*)alloc((size_t)LL * CC * FFD * 2);
  bf16* c_b1  = (bf16*)alloc((size_t)LL * FFD * 2);
  bf16* c_W2  = (bf16*)alloc((size_t)LL * FFD * CC * 2);
  bf16* c_b2  = (bf16*)alloc((size_t)LL * CC * 2);
  bf16* c_l1g = (bf16*)alloc((size_t)LL * CC * 2);
  bf16* c_l1b = (bf16*)alloc((size_t)LL * CC * 2);
  bf16* c_l2g = (bf16*)alloc((size_t)LL * CC * 2);
  bf16* c_l2b = (bf16*)alloc((size_t)LL * CC * 2);
  bf16* c_lfg = (bf16*)alloc((size_t)CC * 2);
  bf16* c_lfb = (bf16*)alloc((size_t)CC * 2);
  bf16* c_Wlm = (bf16*)alloc((size_t)CC * VV * 2);
  bf16* c_blm = (bf16*)alloc((size_t)VV * 2);
  bf16* wqr = (bf16*)alloc((size_t)LL * CC * 256 * 2);
  bf16* wkr = (bf16*)alloc((size_t)LL * CC * 256 * 2);
  bf16* wvr = (bf16*)alloc((size_t)LL * CC * 256 * 2);
  float* loss = (float*)alloc(256);
  int*   flag = (int*)alloc(256);

  hipMemsetAsync(loss, 0, 4, stream);

  detect_kernel<<<1, 256, 0, stream>>>((const unsigned short*)tok, flag);

  auto conv = [&](const void* src, bf16* dst, int n) {
    convert_kernel<<<(n + 255) / 256, 256, 0, stream>>>(src, dst, n, flag);
  };
  conv(tok,  c_tok, VV * CC);
  conv(pos,  c_pos, TT * CC);
  conv(Wo,   c_Wo,  LL * 256 * CC);
  conv(bo,   c_bo,  LL * CC);
  conv(W1,   c_W1,  LL * CC * FFD);
  conv(b1,   c_b1,  LL * FFD);
  conv(W2,   c_W2,  LL * FFD * CC);
  conv(b2,   c_b2,  LL * CC);
  conv(ln1g, c_l1g, LL * CC);
  conv(ln1b, c_l1b, LL * CC);
  conv(ln2g, c_l2g, LL * CC);
  conv(ln2b, c_l2b, LL * CC);
  conv(lnfg, c_lfg, CC);
  conv(lnfb, c_lfb, CC);
  conv(Wlm,  c_Wlm, CC * VV);
  conv(blm,  c_blm, VV);

  int rtot = LL * CC * 256;
  repack_qkv<<<(rtot + 255) / 256, 256, 0, stream>>>(Wq, wqr, rtot, flag);
  repack_qkv<<<(rtot + 255) / 256, 256, 0, stream>>>(Wk, wkr, rtot, flag);
  repack_qkv<<<(rtot + 255) / 256, 256, 0, stream>>>(Wv, wvr, rtot, flag);

  embed_kernel<<<BT, CC, 0, stream>>>(idx, c_tok, c_pos, x);

  for (int l = 0; l < LL; ++l) {
    ln_kernel<<<BT / 4, 256, 0, stream>>>(x, xn, c_l1g + l * CC, c_l1b + l * CC);

    dim3 gq(256 / 64, BT / 64);
    gemm_kernel<OUT_QKV, false><<<gq, 256, 0, stream>>>(xn, wqr + (size_t)l * CC * 256, nullptr, qb, BT, 256, CC);
    gemm_kernel<OUT_QKV, false><<<gq, 256, 0, stream>>>(xn, wkr + (size_t)l * CC * 256, nullptr, kb, BT, 256, CC);
    gemm_kernel<OUT_QKV, false><<<gq, 256, 0, stream>>>(xn, wvr + (size_t)l * CC * 256, nullptr, vb, BT, 256, CC);

    attn_kernel<<<dim3(TT, BB * HH), 256, 0, stream>>>(qb, kb, vb, att);

    gemm_kernel<OUT_RES, false><<<dim3(CC / 64, BT / 64), 256, 0, stream>>>(
        att, c_Wo + (size_t)l * 256 * CC, c_bo + l * CC, x, BT, CC, 256);

    ln_kernel<<<BT / 4, 256, 0, stream>>>(x, xn, c_l2g + l * CC, c_l2b + l * CC);

    for (int ch = 0; ch < BT / FCH; ++ch) {
      const bf16* Ach = xn + (size_t)ch * FCH * CC;
      gemm_kernel<OUT_BF16, true><<<dim3(FFD / 64, FCH / 64), 256, 0, stream>>>(
          Ach, c_W1 + (size_t)l * CC * FFD, c_b1 + l * FFD, ff1, FCH, FFD, CC);
      gemm_kernel<OUT_RES, false><<<dim3(CC / 64, FCH / 64), 256, 0, stream>>>(
          ff1, c_W2 + (size_t)l * FFD * CC, c_b2 + l * CC, x + (size_t)ch * FCH * CC, FCH, CC, FFD);
    }
  }

  ln_kernel<<<BT / 4, 256, 0, stream>>>(x, xn, c_lfg, c_lfb);
  lmhead_kernel<<<BT, 64, 0, stream>>>(xn, c_Wlm, c_blm, targets, d_out, loss, flag);
  finalize_kernel<<<1, 1, 0, stream>>>(loss, d_out, flag);
}

// Round 3
// 9952.126 us; speedup vs baseline: 2.2296x; 2.2296x over previous
//
#include <hip/hip_runtime.h>
#include <hip/hip_bf16.h>

typedef __hip_bfloat16 bf16;

// Problem constants
#define BB   128
#define TT   256
#define CC   384
#define HH   4
#define DH   64
#define LL   6
#define VV   65
#define FFD  1536
#define BT   (BB * TT)   // 32768
#define FCH  16384       // FF row-chunk (2 chunks)

__device__ __forceinline__ float b2f(bf16 h) { return __bfloat162float(h); }
__device__ __forceinline__ bf16  f2b(float f) { return __float2bfloat16(f); }

typedef __bf16 bf16x8 __attribute__((ext_vector_type(8)));
typedef float  f32x4  __attribute__((ext_vector_type(4)));

// global(16B) -> LDS direct copy; LDS dest = wave-uniform base + lane*16
__device__ __forceinline__ void gld_lds16(const void* g, void* l) {
  __builtin_amdgcn_global_load_lds(
      (const __attribute__((address_space(1))) unsigned int*)(unsigned long long)g,
      (__attribute__((address_space(3))) unsigned int*)(unsigned long long)l,
      16, 0, 0);
}

// ---------------------------------------------------------------------------
// Detect input dtype: fp32 (flag=1) vs bf16 (flag=0), via tok_emb bit patterns.
// ---------------------------------------------------------------------------
__global__ __launch_bounds__(256) void detect_kernel(const unsigned short* __restrict__ tok,
                                                     int* __restrict__ flag)
{
  __shared__ int cnt;
  if (threadIdx.x == 0) cnt = 0;
  __syncthreads();
  int c = 0;
  for (int i = threadIdx.x; i < 512; i += 256) {
    int e = (tok[i] >> 7) & 0xFF;
    if (e >= 130) c++;
  }
  atomicAdd(&cnt, c);
  __syncthreads();
  if (threadIdx.x == 0) flag[0] = (cnt > 16) ? 1 : 0;
}

__device__ __forceinline__ float load_flag(const void* src, size_t i, int fl) {
  return fl ? ((const float*)src)[i] : b2f(((const bf16*)src)[i]);
}

// Canonicalize a float tensor (fp32 or bf16 per flag) into bf16.
__global__ __launch_bounds__(256) void convert_kernel(const void* __restrict__ src,
                                                      bf16* __restrict__ dst, int n,
                                                      const int* __restrict__ flag)
{
  int i = blockIdx.x * 256 + threadIdx.x;
  if (i >= n) return;
  dst[i] = f2b(load_flag(src, i, flag[0]));
}

// Generic per-layer transpose: in [L][R][Cc] -> out [L][Cc][R] (bf16), coalesced out.
__global__ __launch_bounds__(256) void transpose_w(const void* __restrict__ src,
                                                   bf16* __restrict__ dst,
                                                   int R, int Cc, int total,
                                                   const int* __restrict__ flag)
{
  int o = blockIdx.x * 256 + threadIdx.x;
  if (o >= total) return;
  int i2 = o % R;
  int j  = (o / R) % Cc;
  int l  = o / (R * Cc);
  dst[o] = f2b(load_flag(src, ((size_t)(l * R + i2)) * Cc + j, flag[0]));
}

// Fused QKV B^T repack: dst[l][n][c] (n in 0..767) from Wq/Wk/Wv [L,H,C,HS].
__global__ __launch_bounds__(256) void repack_qkvT(const void* __restrict__ wq,
                                                   const void* __restrict__ wk,
                                                   const void* __restrict__ wv,
                                                   bf16* __restrict__ dst,
                                                   const int* __restrict__ flag)
{
  int o = blockIdx.x * 256 + threadIdx.x;   // total = LL*768*CC
  if (o >= LL * 768 * CC) return;
  int c = o % CC;
  int n = (o / CC) % 768;
  int l = o / (CC * 768);
  const void* src = (n < 256) ? wq : (n < 512) ? wk : wv;
  int h = (n >> 6) & 3, d = n & 63;
  dst[o] = f2b(load_flag(src, (((size_t)(l * HH + h)) * CC + c) * DH + d, flag[0]));
}

// ---------------------------------------------------------------------------
// Embedding: x[bt, c] = tok_emb[idx[bt], c] + pos_emb[bt % T, c]   (fp32 out)
// ---------------------------------------------------------------------------
__global__ __launch_bounds__(CC) void embed_kernel(
    const int* __restrict__ idx, const bf16* __restrict__ tok,
    const bf16* __restrict__ pos, float* __restrict__ x)
{
  int bt = blockIdx.x;
  int c  = threadIdx.x;
  int tok_id = idx[bt];
  int t = bt & (TT - 1);
  x[(size_t)bt * CC + c] = b2f(tok[(size_t)tok_id * CC + c]) + b2f(pos[(size_t)t * CC + c]);
}

// ---------------------------------------------------------------------------
// LayerNorm: fp32 x row -> bf16 xn row. One wave per row (C=384 -> 6/lane).
// ---------------------------------------------------------------------------
__global__ __launch_bounds__(256) void ln_kernel(
    const float* __restrict__ x, bf16* __restrict__ xn,
    const bf16* __restrict__ g, const bf16* __restrict__ b)
{
  int lane = threadIdx.x & 63;
  int wid  = threadIdx.x >> 6;
  int r = blockIdx.x * 4 + wid;
  const float* xr = x + (size_t)r * CC;
  float vals[6];
  float s = 0.f, ss = 0.f;
#pragma unroll
  for (int i = 0; i < 6; ++i) {
    float v = xr[lane + i * 64];
    vals[i] = v; s += v; ss += v * v;
  }
#pragma unroll
  for (int off = 32; off; off >>= 1) {
    s  += __shfl_xor(s, off, 64);
    ss += __shfl_xor(ss, off, 64);
  }
  float mu   = s * (1.f / CC);
  float var  = ss * (1.f / CC) - mu * mu;
  float rstd = rsqrtf(var + 1e-5f);
  bf16* xo = xn + (size_t)r * CC;
#pragma unroll
  for (int i = 0; i < 6; ++i) {
    int c = lane + i * 64;
    xo[c] = f2b((vals[i] - mu) * rstd * b2f(g[c]) + b2f(b[c]));
  }
}

// ---------------------------------------------------------------------------
// MFMA GEMM: C[M,N] = A[M,K](bf16,row-major) * B(given as B^T [N,K] bf16).
// 128x128 tile, BK=64, 4 waves, 16x16x32 bf16 MFMA, fp32 acc.
// LDS staged via global_load_lds(16B) with XOR-swizzled source, swizzled reads.
// Requires M%128==0, N%128==0, K%64==0.
// ---------------------------------------------------------------------------
enum { OUT_BF16 = 0, OUT_QKV = 1, OUT_RES = 2 };

template<int MODE, bool RELU>
__global__ __launch_bounds__(256) void mfma_gemm(
    const bf16* __restrict__ A, const bf16* __restrict__ Bt,
    const bf16* __restrict__ bias, void* __restrict__ out,
    int M, int N, int K)
{
  __shared__ bf16 As[128 * 64];
  __shared__ bf16 Bs[128 * 64];
  const int tid  = threadIdx.x;
  const int w    = tid >> 6, lane = tid & 63;
  const int m0   = blockIdx.y * 128, n0 = blockIdx.x * 128;
  const int wr   = (w >> 1) * 64, wc = (w & 1) * 64;   // wave's 64x64 origin
  const int lrow = lane & 15, lk = lane >> 4;

  f32x4 acc[4][4] = {};

  // staging constants: wave w stages rows [w*32, w*32+32) of each tile,
  // inst i covers 8 rows; lane L -> row w*32+i*8+(L>>3), phys unit L&7.
  const int srow8 = lane >> 3;          // 0..7
  const int sup   = lane & 7;           // physical 16B unit

  for (int k0 = 0; k0 < K; k0 += 64) {
#pragma unroll
    for (int i = 0; i < 4; ++i) {
      int row  = w * 32 + i * 8 + srow8;
      int ulog = sup ^ (row & 7);       // pre-swizzled global source unit
      gld_lds16(A  + (size_t)(m0 + row) * K + k0 + ulog * 8, &As[(w * 32 + i * 8) * 64]);
      gld_lds16(Bt + (size_t)(n0 + row) * K + k0 + ulog * 8, &Bs[(w * 32 + i * 8) * 64]);
    }
    __syncthreads();
#pragma unroll
    for (int kk = 0; kk < 2; ++kk) {
      bf16x8 af[4], bg[4];
#pragma unroll
      for (int mi = 0; mi < 4; ++mi) {
        int r = wr + mi * 16 + lrow;
        int u = (kk * 4 + lk) ^ (r & 7);  // swizzled read
        af[mi] = *reinterpret_cast<const bf16x8*>(&As[r * 64 + u * 8]);
      }
#pragma unroll
      for (int ni = 0; ni < 4; ++ni) {
        int r = wc + ni * 16 + lrow;
        int u = (kk * 4 + lk) ^ (r & 7);
        bg[ni] = *reinterpret_cast<const bf16x8*>(&Bs[r * 64 + u * 8]);
      }
#pragma unroll
      for (int mi = 0; mi < 4; ++mi)
#pragma unroll
        for (int ni = 0; ni < 4; ++ni)
          acc[mi][ni] = __builtin_amdgcn_mfma_f32_16x16x32_bf16(af[mi], bg[ni], acc[mi][ni], 0, 0, 0);
    }
    __syncthreads();
  }

  // Epilogue. D layout: col = lane&15, row = (lane>>4)*4 + r  [m89-verified]
#pragma unroll
  for (int mi = 0; mi < 4; ++mi) {
#pragma unroll
    for (int ni = 0; ni < 4; ++ni) {
#pragma unroll
      for (int r = 0; r < 4; ++r) {
        int m = m0 + wr + mi * 16 + lk * 4 + r;
        int n = n0 + wc + ni * 16 + lrow;
        float v = acc[mi][ni][r];
        if (MODE == OUT_BF16) {
          v += b2f(bias[n]);
          if (RELU) v = fmaxf(v, 0.f);
          reinterpret_cast<bf16*>(out)[(size_t)m * N + n] = f2b(v);
        } else if (MODE == OUT_RES) {
          v += b2f(bias[n]);
          reinterpret_cast<float*>(out)[(size_t)m * N + n] += v;  // fp32 residual
        } else {  // OUT_QKV: n<256 q, <512 k, else v; scatter to [B,H,T,DH]
          int which = n >> 8;
          int h = (n >> 6) & 3, d = n & 63;
          int b = m >> 8, trow = m & 255;
          reinterpret_cast<bf16*>(out)[(size_t)which * BB * HH * TT * DH +
              (((size_t)b * HH + h) * TT + trow) * DH + d] = f2b(v);
        }
      }
    }
  }
}

// ---------------------------------------------------------------------------
// Fused causal attention: one block per (b,h,t). Scores+softmax+PV in LDS.
// q,k,v: [B,H,T,HS] bf16.  att out: [B,T,H*HS] bf16.
// ---------------------------------------------------------------------------
__global__ __launch_bounds__(256) void attn_kernel(
    const bf16* __restrict__ q, const bf16* __restrict__ kptr,
    const bf16* __restrict__ vptr, bf16* __restrict__ att)
{
  int t   = blockIdx.x;
  int bh  = blockIdx.y;            // b*H + h
  int tid = threadIdx.x;
  int lane = tid & 63, wid = tid >> 6;
  __shared__ float qs[DH];
  __shared__ float wei[TT];
  __shared__ float wmax[4], wsum[4];
  __shared__ float pv[4][DH];

  const bf16* qrow = q + ((size_t)bh * TT + t) * DH;
  if (tid < DH) qs[tid] = b2f(qrow[tid]);
  __syncthreads();

  int s = tid;                     // blockDim == T == 256
  float sc = -INFINITY;
  if (s <= t) {
    const bf16* krow = kptr + ((size_t)bh * TT + s) * DH;
    float a = 0.f;
#pragma unroll
    for (int d = 0; d < DH; d += 4) {
      ushort4 u = *reinterpret_cast<const ushort4*>(krow + d);
      a += qs[d]     * __uint_as_float((unsigned)u.x << 16);
      a += qs[d + 1] * __uint_as_float((unsigned)u.y << 16);
      a += qs[d + 2] * __uint_as_float((unsigned)u.z << 16);
      a += qs[d + 3] * __uint_as_float((unsigned)u.w << 16);
    }
    sc = a * 0.125f;               // HS^-0.5
  }
  float m = sc;
#pragma unroll
  for (int off = 32; off; off >>= 1) m = fmaxf(m, __shfl_xor(m, off, 64));
  if (lane == 0) wmax[wid] = m;
  __syncthreads();
  float mx = fmaxf(fmaxf(wmax[0], wmax[1]), fmaxf(wmax[2], wmax[3]));
  float e = (s <= t) ? __expf(sc - mx) : 0.f;
  wei[s] = e;
  float sum = e;
#pragma unroll
  for (int off = 32; off; off >>= 1) sum += __shfl_xor(sum, off, 64);
  if (lane == 0) wsum[wid] = sum;
  __syncthreads();
  float denom = wsum[0] + wsum[1] + wsum[2] + wsum[3];

  // PV: thread = (quarter of s-range, d)
  int d  = tid & 63, qd = tid >> 6;
  float a = 0.f;
  int s0 = qd * 64, s1 = min(s0 + 64, t + 1);
  for (int s2 = s0; s2 < s1; ++s2)
    a += wei[s2] * b2f(vptr[((size_t)bh * TT + s2) * DH + d]);
  pv[qd][d] = a;
  __syncthreads();
  if (tid < DH) {
    float o = (pv[0][tid] + pv[1][tid] + pv[2][tid] + pv[3][tid]) / denom;
    int b = bh >> 2, h = bh & 3;   // H = 4
    att[(((size_t)b * TT + t) * HH + h) * DH + tid] = f2b(o);
  }
}

// ---------------------------------------------------------------------------
// LM head + log-softmax + loss. One wave per row; lane n covers col n,
// lane 0 additionally covers col 64 (V=65). Logits -> d_out (dtype per flag).
// ---------------------------------------------------------------------------
__global__ __launch_bounds__(64) void lmhead_kernel(
    const bf16* __restrict__ xn, const bf16* __restrict__ Wlm,
    const bf16* __restrict__ blm, const int* __restrict__ targets,
    void* __restrict__ out, float* __restrict__ loss,
    const int* __restrict__ flag)
{
  int r = blockIdx.x;
  int lane = threadIdx.x;
  __shared__ float xs[CC];
#pragma unroll
  for (int i = 0; i < CC / 64; ++i) xs[lane + i * 64] = b2f(xn[(size_t)r * CC + lane + i * 64]);
  __syncthreads();
  float a0 = 0.f, a1 = 0.f;
  for (int c = 0; c < CC; ++c) {
    float xv = xs[c];
    a0 += xv * b2f(Wlm[(size_t)c * VV + lane]);
    if (lane == 0) a1 += xv * b2f(Wlm[(size_t)c * VV + 64]);
  }
  a0 += b2f(blm[lane]);
  if (lane == 0) a1 += b2f(blm[64]);
  if (flag[0]) {
    float* o = (float*)out;
    o[(size_t)r * VV + lane] = a0;
    if (lane == 0) o[(size_t)r * VV + 64] = a1;
  } else {
    bf16* o = (bf16*)out;
    o[(size_t)r * VV + lane] = f2b(a0);
    if (lane == 0) o[(size_t)r * VV + 64] = f2b(a1);
  }

  float m = (lane == 0) ? fmaxf(a0, a1) : a0;
#pragma unroll
  for (int off = 32; off; off >>= 1) m = fmaxf(m, __shfl_xor(m, off, 64));
  float e = __expf(a0 - m) + ((lane == 0) ? __expf(a1 - m) : 0.f);
#pragma unroll
  for (int off = 32; off; off >>= 1) e += __shfl_xor(e, off, 64);
  float logZ = m + logf(e);
  int tgt = targets[r];
  float contrib = (lane == tgt) ? (a0 - logZ) : 0.f;
  if (lane == 0 && tgt == 64) contrib = a1 - logZ;
#pragma unroll
  for (int off = 32; off; off >>= 1) contrib += __shfl_xor(contrib, off, 64);
  if (lane == 0) atomicAdd(loss, -contrib);
}

__global__ void finalize_kernel(const float* __restrict__ loss, void* __restrict__ out,
                                const int* __restrict__ flag)
{
  float v = loss[0] * (1.f / BT);
  if (flag[0]) ((float*)out)[(size_t)BT * VV] = v;
  else         ((bf16*)out)[(size_t)BT * VV]  = f2b(v);
}

// ---------------------------------------------------------------------------
extern "C" void kernel_launch(void* const* d_in, const int* in_sizes, int n_in,
                              void* d_out, int out_size, void* d_ws, size_t ws_size,
                              hipStream_t stream)
{
  const int* idx     = (const int*)d_in[0];
  const int* targets = (const int*)d_in[1];
  const void* tok  = d_in[2];
  const void* pos  = d_in[3];
  const void* Wq   = d_in[4];
  const void* Wk   = d_in[5];
  const void* Wv   = d_in[6];
  const void* Wo   = d_in[7];
  const void* bo   = d_in[8];
  const void* W1   = d_in[9];
  const void* b1   = d_in[10];
  const void* W2   = d_in[11];
  const void* b2   = d_in[12];
  const void* ln1g = d_in[13];
  const void* ln1b = d_in[14];
  const void* ln2g = d_in[15];
  const void* ln2b = d_in[16];
  const void* lnfg = d_in[17];
  const void* lnfb = d_in[18];
  const void* Wlm  = d_in[19];
  const void* blm  = d_in[20];

  char* ws = (char*)d_ws;
  size_t off = 0;
  auto alloc = [&](size_t bytes) { void* p = ws + off; off += (bytes + 255) & ~(size_t)255; return p; };

  float* x   = (float*)alloc((size_t)BT * CC * 4);            // 50.3 MB
  bf16*  xn  = (bf16*)alloc((size_t)BT * CC * 2);             // 25.2 MB
  bf16*  qb  = (bf16*)alloc((size_t)BB * HH * TT * DH * 2);   // 16.8 MB x3 (contiguous)
  bf16*  kb  = (bf16*)alloc((size_t)BB * HH * TT * DH * 2);
  bf16*  vb  = (bf16*)alloc((size_t)BB * HH * TT * DH * 2);
  bf16*  att = (bf16*)alloc((size_t)BT * 256 * 2);            // 16.8 MB
  bf16*  ff1 = qb;   // FF phase aliases dead q/k/v buffers (FCH*FFD*2 = 50.33MB = qkv exactly)
  // canonical bf16 weights
  bf16* c_tok  = (bf16*)alloc((size_t)VV * CC * 2);
  bf16* c_pos  = (bf16*)alloc((size_t)TT * CC * 2);
  bf16* wqkvT  = (bf16*)alloc((size_t)LL * 768 * CC * 2);     // B^T for fused QKV
  bf16* woT    = (bf16*)alloc((size_t)LL * CC * 256 * 2);     // B^T [C][256]
  bf16* w1T    = (bf16*)alloc((size_t)LL * FFD * CC * 2);     // B^T [FFD][C]
  bf16* w2T    = (bf16*)alloc((size_t)LL * CC * FFD * 2);     // B^T [C][FFD]
  bf16* c_bo   = (bf16*)alloc((size_t)LL * CC * 2);
  bf16* c_b1   = (bf16*)alloc((size_t)LL * FFD * 2);
  bf16* c_b2   = (bf16*)alloc((size_t)LL * CC * 2);
  bf16* c_l1g  = (bf16*)alloc((size_t)LL * CC * 2);
  bf16* c_l1b  = (bf16*)alloc((size_t)LL * CC * 2);
  bf16* c_l2g  = (bf16*)alloc((size_t)LL * CC * 2);
  bf16* c_l2b  = (bf16*)alloc((size_t)LL * CC * 2);
  bf16* c_lfg  = (bf16*)alloc((size_t)CC * 2);
  bf16* c_lfb  = (bf16*)alloc((size_t)CC * 2);
  bf16* c_Wlm  = (bf16*)alloc((size_t)CC * VV * 2);
  bf16* c_blm  = (bf16*)alloc((size_t)VV * 2);
  float* loss  = (float*)alloc(256);
  int*   flag  = (int*)alloc(256);

  hipMemsetAsync(loss, 0, 4, stream);

  detect_kernel<<<1, 256, 0, stream>>>((const unsigned short*)tok, flag);

  auto conv = [&](const void* src, bf16* dst, int n) {
    convert_kernel<<<(n + 255) / 256, 256, 0, stream>>>(src, dst, n, flag);
  };
  conv(tok,  c_tok, VV * CC);
  conv(pos,  c_pos, TT * CC);
  conv(bo,   c_bo,  LL * CC);
  conv(b1,   c_b1,  LL * FFD);
  conv(b2,   c_b2,  LL * CC);
  conv(ln1g, c_l1g, LL * CC);
  conv(ln1b, c_l1b, LL * CC);
  conv(ln2g, c_l2g, LL * CC);
  conv(ln2b, c_l2b, LL * CC);
  conv(lnfg, c_lfg, CC);
  conv(lnfb, c_lfb, CC);
  conv(Wlm,  c_Wlm, CC * VV);
  conv(blm,  c_blm, VV);

  {
    int tq = LL * 768 * CC;
    repack_qkvT<<<(tq + 255) / 256, 256, 0, stream>>>(Wq, Wk, Wv, wqkvT, flag);
    int t1 = LL * 256 * CC;
    transpose_w<<<(t1 + 255) / 256, 256, 0, stream>>>(Wo, woT, 256, CC, t1, flag);
    int t2 = LL * CC * FFD;
    transpose_w<<<(t2 + 255) / 256, 256, 0, stream>>>(W1, w1T, CC, FFD, t2, flag);
    transpose_w<<<(t2 + 255) / 256, 256, 0, stream>>>(W2, w2T, FFD, CC, t2, flag);
  }

  embed_kernel<<<BT, CC, 0, stream>>>(idx, c_tok, c_pos, x);

  for (int l = 0; l < LL; ++l) {
    ln_kernel<<<BT / 4, 256, 0, stream>>>(x, xn, c_l1g + l * CC, c_l1b + l * CC);

    // fused QKV: [BT,768] = xn[BT,384] * WqkvT^T ; scatter to qb/kb/vb
    mfma_gemm<OUT_QKV, false><<<dim3(768 / 128, BT / 128), 256, 0, stream>>>(
        xn, wqkvT + (size_t)l * 768 * CC, nullptr, qb, BT, 768, CC);

    attn_kernel<<<dim3(TT, BB * HH), 256, 0, stream>>>(qb, kb, vb, att);

    mfma_gemm<OUT_RES, false><<<dim3(CC / 128, BT / 128), 256, 0, stream>>>(
        att, woT + (size_t)l * CC * 256, c_bo + l * CC, x, BT, CC, 256);

    ln_kernel<<<BT / 4, 256, 0, stream>>>(x, xn, c_l2g + l * CC, c_l2b + l * CC);

    for (int ch = 0; ch < BT / FCH; ++ch) {
      const bf16* Ach = xn + (size_t)ch * FCH * CC;
      mfma_gemm<OUT_BF16, true><<<dim3(FFD / 128, FCH / 128), 256, 0, stream>>>(
          Ach, w1T + (size_t)l * FFD * CC, c_b1 + l * FFD, ff1, FCH, FFD, CC);
      mfma_gemm<OUT_RES, false><<<dim3(CC / 128, FCH / 128), 256, 0, stream>>>(
          ff1, w2T + (size_t)l * CC * FFD, c_b2 + l * CC, x + (size_t)ch * FCH * CC, FCH, CC, FFD);
    }
  }

  ln_kernel<<<BT / 4, 256, 0, stream>>>(x, xn, c_lfg, c_lfb);
  lmhead_kernel<<<BT, 64, 0, stream>>>(xn, c_Wlm, c_blm, targets, d_out, loss, flag);
  finalize_kernel<<<1, 1, 0, stream>>>(loss, d_out, flag);
}

// Round 4
// 2432.112 us; speedup vs baseline: 9.1236x; 4.0920x over previous
//
#include <hip/hip_runtime.h>
#include <hip/hip_bf16.h>

typedef __hip_bfloat16 bf16;

// Problem constants
#define BB   128
#define TT   256
#define CC   384
#define HH   4
#define DH   64
#define LL   6
#define VV   65
#define FFD  1536
#define BT   (BB * TT)   // 32768
#define FCH  16384       // FF row-chunk (2 chunks)

__device__ __forceinline__ float b2f(bf16 h) { return __bfloat162float(h); }
__device__ __forceinline__ bf16  f2b(float f) { return __float2bfloat16(f); }

typedef __bf16 bf16x8 __attribute__((ext_vector_type(8)));
typedef float  f32x4  __attribute__((ext_vector_type(4)));

__device__ __forceinline__ __bf16 f2n(float f) {
  bf16 h = f2b(f);
  return __builtin_bit_cast(__bf16, h);
}

// global(16B) -> LDS direct copy; LDS dest = wave-uniform base + lane*16
__device__ __forceinline__ void gld_lds16(const void* g, void* l) {
  __builtin_amdgcn_global_load_lds(
      (const __attribute__((address_space(1))) unsigned int*)(unsigned long long)g,
      (__attribute__((address_space(3))) unsigned int*)(unsigned long long)l,
      16, 0, 0);
}

// ---------------------------------------------------------------------------
// Detect input dtype: fp32 (flag=1) vs bf16 (flag=0), via tok_emb bit patterns.
// ---------------------------------------------------------------------------
__global__ __launch_bounds__(256) void detect_kernel(const unsigned short* __restrict__ tok,
                                                     int* __restrict__ flag)
{
  __shared__ int cnt;
  if (threadIdx.x == 0) cnt = 0;
  __syncthreads();
  int c = 0;
  for (int i = threadIdx.x; i < 512; i += 256) {
    int e = (tok[i] >> 7) & 0xFF;
    if (e >= 130) c++;
  }
  atomicAdd(&cnt, c);
  __syncthreads();
  if (threadIdx.x == 0) flag[0] = (cnt > 16) ? 1 : 0;
}

__device__ __forceinline__ float load_flag(const void* src, size_t i, int fl) {
  return fl ? ((const float*)src)[i] : b2f(((const bf16*)src)[i]);
}

// Canonicalize a float tensor (fp32 or bf16 per flag) into bf16.
__global__ __launch_bounds__(256) void convert_kernel(const void* __restrict__ src,
                                                      bf16* __restrict__ dst, int n,
                                                      const int* __restrict__ flag)
{
  int i = blockIdx.x * 256 + threadIdx.x;
  if (i >= n) return;
  dst[i] = f2b(load_flag(src, i, flag[0]));
}

// Generic per-layer transpose: in [L][R][Cc] -> out [L][Cc][R] (bf16), coalesced out.
__global__ __launch_bounds__(256) void transpose_w(const void* __restrict__ src,
                                                   bf16* __restrict__ dst,
                                                   int R, int Cc, int total,
                                                   const int* __restrict__ flag)
{
  int o = blockIdx.x * 256 + threadIdx.x;
  if (o >= total) return;
  int i2 = o % R;
  int j  = (o / R) % Cc;
  int l  = o / (R * Cc);
  dst[o] = f2b(load_flag(src, ((size_t)(l * R + i2)) * Cc + j, flag[0]));
}

// Fused QKV B^T repack: dst[l][n][c] (n in 0..767) from Wq/Wk/Wv [L,H,C,HS].
__global__ __launch_bounds__(256) void repack_qkvT(const void* __restrict__ wq,
                                                   const void* __restrict__ wk,
                                                   const void* __restrict__ wv,
                                                   bf16* __restrict__ dst,
                                                   const int* __restrict__ flag)
{
  int o = blockIdx.x * 256 + threadIdx.x;   // total = LL*768*CC
  if (o >= LL * 768 * CC) return;
  int c = o % CC;
  int n = (o / CC) % 768;
  int l = o / (CC * 768);
  const void* src = (n < 256) ? wq : (n < 512) ? wk : wv;
  int h = (n >> 6) & 3, d = n & 63;
  dst[o] = f2b(load_flag(src, (((size_t)(l * HH + h)) * CC + c) * DH + d, flag[0]));
}

// ---------------------------------------------------------------------------
// Embedding: x[bt, c] = tok_emb[idx[bt], c] + pos_emb[bt % T, c]   (fp32 out)
// ---------------------------------------------------------------------------
__global__ __launch_bounds__(CC) void embed_kernel(
    const int* __restrict__ idx, const bf16* __restrict__ tok,
    const bf16* __restrict__ pos, float* __restrict__ x)
{
  int bt = blockIdx.x;
  int c  = threadIdx.x;
  int tok_id = idx[bt];
  int t = bt & (TT - 1);
  x[(size_t)bt * CC + c] = b2f(tok[(size_t)tok_id * CC + c]) + b2f(pos[(size_t)t * CC + c]);
}

// ---------------------------------------------------------------------------
// LayerNorm: fp32 x row -> bf16 xn row. One wave per row (C=384 -> 6/lane).
// ---------------------------------------------------------------------------
__global__ __launch_bounds__(256) void ln_kernel(
    const float* __restrict__ x, bf16* __restrict__ xn,
    const bf16* __restrict__ g, const bf16* __restrict__ b)
{
  int lane = threadIdx.x & 63;
  int wid  = threadIdx.x >> 6;
  int r = blockIdx.x * 4 + wid;
  const float* xr = x + (size_t)r * CC;
  float vals[6];
  float s = 0.f, ss = 0.f;
#pragma unroll
  for (int i = 0; i < 6; ++i) {
    float v = xr[lane + i * 64];
    vals[i] = v; s += v; ss += v * v;
  }
#pragma unroll
  for (int off = 32; off; off >>= 1) {
    s  += __shfl_xor(s, off, 64);
    ss += __shfl_xor(ss, off, 64);
  }
  float mu   = s * (1.f / CC);
  float var  = ss * (1.f / CC) - mu * mu;
  float rstd = rsqrtf(var + 1e-5f);
  bf16* xo = xn + (size_t)r * CC;
#pragma unroll
  for (int i = 0; i < 6; ++i) {
    int c = lane + i * 64;
    xo[c] = f2b((vals[i] - mu) * rstd * b2f(g[c]) + b2f(b[c]));
  }
}

// ---------------------------------------------------------------------------
// MFMA GEMM: C[M,N] = A[M,K](bf16,row-major) * B(given as B^T [N,K] bf16).
// 128x128 tile, BK=64, 4 waves, 16x16x32 bf16 MFMA, fp32 acc.
// ---------------------------------------------------------------------------
enum { OUT_BF16 = 0, OUT_QKV = 1, OUT_RES = 2 };

template<int MODE, bool RELU>
__global__ __launch_bounds__(256) void mfma_gemm(
    const bf16* __restrict__ A, const bf16* __restrict__ Bt,
    const bf16* __restrict__ bias, void* __restrict__ out,
    int M, int N, int K)
{
  __shared__ bf16 As[128 * 64];
  __shared__ bf16 Bs[128 * 64];
  const int tid  = threadIdx.x;
  const int w    = tid >> 6, lane = tid & 63;
  const int m0   = blockIdx.y * 128, n0 = blockIdx.x * 128;
  const int wr   = (w >> 1) * 64, wc = (w & 1) * 64;   // wave's 64x64 origin
  const int lrow = lane & 15, lk = lane >> 4;

  f32x4 acc[4][4] = {};

  const int srow8 = lane >> 3;          // 0..7
  const int sup   = lane & 7;           // physical 16B unit

  for (int k0 = 0; k0 < K; k0 += 64) {
#pragma unroll
    for (int i = 0; i < 4; ++i) {
      int row  = w * 32 + i * 8 + srow8;
      int ulog = sup ^ (row & 7);       // pre-swizzled global source unit
      gld_lds16(A  + (size_t)(m0 + row) * K + k0 + ulog * 8, &As[(w * 32 + i * 8) * 64]);
      gld_lds16(Bt + (size_t)(n0 + row) * K + k0 + ulog * 8, &Bs[(w * 32 + i * 8) * 64]);
    }
    __syncthreads();
#pragma unroll
    for (int kk = 0; kk < 2; ++kk) {
      bf16x8 af[4], bg[4];
#pragma unroll
      for (int mi = 0; mi < 4; ++mi) {
        int r = wr + mi * 16 + lrow;
        int u = (kk * 4 + lk) ^ (r & 7);  // swizzled read
        af[mi] = *reinterpret_cast<const bf16x8*>(&As[r * 64 + u * 8]);
      }
#pragma unroll
      for (int ni = 0; ni < 4; ++ni) {
        int r = wc + ni * 16 + lrow;
        int u = (kk * 4 + lk) ^ (r & 7);
        bg[ni] = *reinterpret_cast<const bf16x8*>(&Bs[r * 64 + u * 8]);
      }
#pragma unroll
      for (int mi = 0; mi < 4; ++mi)
#pragma unroll
        for (int ni = 0; ni < 4; ++ni)
          acc[mi][ni] = __builtin_amdgcn_mfma_f32_16x16x32_bf16(af[mi], bg[ni], acc[mi][ni], 0, 0, 0);
    }
    __syncthreads();
  }

  // Epilogue. D layout: col = lane&15, row = (lane>>4)*4 + r
#pragma unroll
  for (int mi = 0; mi < 4; ++mi) {
#pragma unroll
    for (int ni = 0; ni < 4; ++ni) {
#pragma unroll
      for (int r = 0; r < 4; ++r) {
        int m = m0 + wr + mi * 16 + lk * 4 + r;
        int n = n0 + wc + ni * 16 + lrow;
        float v = acc[mi][ni][r];
        if (MODE == OUT_BF16) {
          v += b2f(bias[n]);
          if (RELU) v = fmaxf(v, 0.f);
          reinterpret_cast<bf16*>(out)[(size_t)m * N + n] = f2b(v);
        } else if (MODE == OUT_RES) {
          v += b2f(bias[n]);
          reinterpret_cast<float*>(out)[(size_t)m * N + n] += v;  // fp32 residual
        } else {  // OUT_QKV: n<256 q, <512 k, else v; scatter to [B,H,T,DH]
          int which = n >> 8;
          int h = (n >> 6) & 3, d = n & 63;
          int b = m >> 8, trow = m & 255;
          reinterpret_cast<bf16*>(out)[(size_t)which * BB * HH * TT * DH +
              (((size_t)b * HH + h) * TT + trow) * DH + d] = f2b(v);
        }
      }
    }
  }
}

// ---------------------------------------------------------------------------
// MFMA flash attention. One block per (b,h), 512 threads (8 waves).
// Wave w handles q-tiles {w, 15-w} (16 rows each). Full S row kept in regs.
// LDS: 16KB shared stage (K chunk [128][64] OR Vt chunk [64][128], both
// XOR-unit-swizzled) + per-wave P staging [16][128] (swizzled).
// Fragment layouts identical to mfma_gemm (verified by rounds 2/3).
// ---------------------------------------------------------------------------
__global__ __launch_bounds__(512) void attn_mfma_kernel(
    const bf16* __restrict__ qg, const bf16* __restrict__ kg,
    const bf16* __restrict__ vg, bf16* __restrict__ att)
{
  __shared__ __bf16 stage[128 * 64];        // 16KB: K chunk or Vt chunk
  __shared__ __bf16 Pbuf[8][16 * 128];      // 32KB: per-wave P staging
  const int bh = blockIdx.x;
  const int b  = bh >> 2, h = bh & 3;       // H = 4
  const int tid = threadIdx.x, w = tid >> 6, lane = tid & 63;
  const int l15 = lane & 15, lk = lane >> 4;
  const bf16* Qg = qg + (size_t)bh * TT * DH;
  const bf16* Kg = kg + (size_t)bh * TT * DH;
  const bf16* Vg = vg + (size_t)bh * TT * DH;
  __bf16* Pw = &Pbuf[w][0];

  for (int qp = 0; qp < 2; ++qp) {
    const int qt = qp ? (15 - w) : w;       // this wave's q-tile (runtime scalar, fine)
    const int mrow0 = qt * 16 + lk * 4;     // +r = global query row of C-layout reg r

    // Q fragments (A-frag direct from global): lane&15 = row, octet kk*4+lk
    bf16x8 aq[2];
#pragma unroll
    for (int kk = 0; kk < 2; ++kk)
      aq[kk] = *reinterpret_cast<const bf16x8*>(Qg + (size_t)(qt * 16 + l15) * DH + (kk * 4 + lk) * 8);

    f32x4 sc[16];
#pragma unroll
    for (int ct = 0; ct < 16; ++ct) sc[ct] = (f32x4){0.f, 0.f, 0.f, 0.f};

    // ---- S = Q K^T over two K chunks of 128 rows ----
#pragma unroll
    for (int c = 0; c < 2; ++c) {
      {  // stage K chunk c: wave stages rows [w*16, w*16+16)
        int rl = w * 16;
#pragma unroll
        for (int i = 0; i < 2; ++i) {
          int row  = rl + i * 8 + (lane >> 3);
          int ulog = (lane & 7) ^ (row & 7);
          gld_lds16(Kg + (size_t)(c * 128 + row) * DH + ulog * 8, &stage[(rl + i * 8) * DH]);
        }
      }
      __syncthreads();
#pragma unroll
      for (int ctl = 0; ctl < 8; ++ctl) {
        int srow = ctl * 16 + l15;          // chunk-local key row (B-frag: lane&15 = n)
        int ct = c * 8 + ctl;
#pragma unroll
        for (int kk = 0; kk < 2; ++kk) {
          bf16x8 kf = *reinterpret_cast<const bf16x8*>(
              &stage[srow * DH + (((kk * 4 + lk) ^ (srow & 7)) * 8)]);
          sc[ct] = __builtin_amdgcn_mfma_f32_16x16x32_bf16(aq[kk], kf, sc[ct], 0, 0, 0);
        }
      }
      __syncthreads();
    }

    // ---- softmax (registers only; rows are lane-local in C-layout) ----
    float mr[4] = {-1e30f, -1e30f, -1e30f, -1e30f};
#pragma unroll
    for (int ct = 0; ct < 16; ++ct) {
      int s = ct * 16 + l15;
#pragma unroll
      for (int r = 0; r < 4; ++r) {
        float v = sc[ct][r] * 0.125f;       // HS^-0.5
        if (s > mrow0 + r) v = -1e30f;      // causal mask
        sc[ct][r] = v;
        mr[r] = fmaxf(mr[r], v);
      }
    }
#pragma unroll
    for (int off = 8; off; off >>= 1)
#pragma unroll
      for (int r = 0; r < 4; ++r) mr[r] = fmaxf(mr[r], __shfl_xor(mr[r], off, 64));
    float dsum[4] = {0.f, 0.f, 0.f, 0.f};
#pragma unroll
    for (int ct = 0; ct < 16; ++ct)
#pragma unroll
      for (int r = 0; r < 4; ++r) {
        float e = __expf(sc[ct][r] - mr[r]);
        sc[ct][r] = e;
        dsum[r] += e;
      }
#pragma unroll
    for (int off = 8; off; off >>= 1)
#pragma unroll
      for (int r = 0; r < 4; ++r) dsum[r] += __shfl_xor(dsum[r], off, 64);
    float rd[4];
#pragma unroll
    for (int r = 0; r < 4; ++r) rd[r] = 1.f / dsum[r];

    // ---- O = P V over two V chunks of 128 keys ----
    f32x4 o[4];
#pragma unroll
    for (int nt = 0; nt < 4; ++nt) o[nt] = (f32x4){0.f, 0.f, 0.f, 0.f};

#pragma unroll
    for (int c = 0; c < 2; ++c) {
      {  // stage Vt chunk c (transpose): wave owns d rows [w*8, w*8+8)
        int d0 = w * 8;
#pragma unroll
        for (int it = 0; it < 2; ++it) {
          int sl = it * 64 + lane;
          bf16x8 vv = *reinterpret_cast<const bf16x8*>(Vg + (size_t)(c * 128 + sl) * DH + d0);
#pragma unroll
          for (int j = 0; j < 8; ++j) {
            int u = (sl >> 3) ^ j;          // phys unit = (s>>3) ^ (d&7), d&7 == j
            stage[(d0 + j) * 128 + u * 8 + (sl & 7)] = vv[j];
          }
        }
      }
      __syncthreads();
      // write P chunk c (wave-private; cols ct = c*8 .. c*8+7)
#pragma unroll
      for (int ctl = 0; ctl < 8; ++ctl) {
        int sl = ctl * 16 + l15;
        int u  = sl >> 3;
#pragma unroll
        for (int r = 0; r < 4; ++r) {
          int row = lk * 4 + r;
          Pw[row * 128 + ((u ^ (row & 7)) * 8) + (sl & 7)] = f2n(sc[c * 8 + ctl][r]);
        }
      }
      // PV: A-frag from Pw, B-frag from Vt (in-order DS pipe gives same-wave RAW)
#pragma unroll
      for (int ks = 0; ks < 4; ++ks) {
        bf16x8 pf = *reinterpret_cast<const bf16x8*>(
            &Pw[l15 * 128 + (((ks * 4 + lk) ^ (l15 & 7)) * 8)]);
#pragma unroll
        for (int nt = 0; nt < 4; ++nt) {
          int dd = nt * 16 + l15;
          bf16x8 vf = *reinterpret_cast<const bf16x8*>(
              &stage[dd * 128 + (((ks * 4 + lk) ^ (dd & 7)) * 8)]);
          o[nt] = __builtin_amdgcn_mfma_f32_16x16x32_bf16(pf, vf, o[nt], 0, 0, 0);
        }
      }
      __syncthreads();
    }

    // ---- epilogue: att[b][t][h*64+d], rows match C-layout regs ----
#pragma unroll
    for (int nt = 0; nt < 4; ++nt)
#pragma unroll
      for (int r = 0; r < 4; ++r) {
        int t = qt * 16 + lk * 4 + r;
        int d = nt * 16 + l15;
        att[(((size_t)b * TT + t) * HH + h) * DH + d] = f2b(o[nt][r] * rd[r]);
      }
    __syncthreads();   // protect `stage` before next q-tile restages K
  }
}

// ---------------------------------------------------------------------------
// LM head + log-softmax + loss. One wave per row; lane n covers col n,
// lane 0 additionally covers col 64 (V=65). Logits -> d_out (dtype per flag).
// ---------------------------------------------------------------------------
__global__ __launch_bounds__(64) void lmhead_kernel(
    const bf16* __restrict__ xn, const bf16* __restrict__ Wlm,
    const bf16* __restrict__ blm, const int* __restrict__ targets,
    void* __restrict__ out, float* __restrict__ loss,
    const int* __restrict__ flag)
{
  int r = blockIdx.x;
  int lane = threadIdx.x;
  __shared__ float xs[CC];
#pragma unroll
  for (int i = 0; i < CC / 64; ++i) xs[lane + i * 64] = b2f(xn[(size_t)r * CC + lane + i * 64]);
  __syncthreads();
  float a0 = 0.f, a1 = 0.f;
  for (int c = 0; c < CC; ++c) {
    float xv = xs[c];
    a0 += xv * b2f(Wlm[(size_t)c * VV + lane]);
    if (lane == 0) a1 += xv * b2f(Wlm[(size_t)c * VV + 64]);
  }
  a0 += b2f(blm[lane]);
  if (lane == 0) a1 += b2f(blm[64]);
  if (flag[0]) {
    float* o = (float*)out;
    o[(size_t)r * VV + lane] = a0;
    if (lane == 0) o[(size_t)r * VV + 64] = a1;
  } else {
    bf16* o = (bf16*)out;
    o[(size_t)r * VV + lane] = f2b(a0);
    if (lane == 0) o[(size_t)r * VV + 64] = f2b(a1);
  }

  float m = (lane == 0) ? fmaxf(a0, a1) : a0;
#pragma unroll
  for (int off = 32; off; off >>= 1) m = fmaxf(m, __shfl_xor(m, off, 64));
  float e = __expf(a0 - m) + ((lane == 0) ? __expf(a1 - m) : 0.f);
#pragma unroll
  for (int off = 32; off; off >>= 1) e += __shfl_xor(e, off, 64);
  float logZ = m + logf(e);
  int tgt = targets[r];
  float contrib = (lane == tgt) ? (a0 - logZ) : 0.f;
  if (lane == 0 && tgt == 64) contrib = a1 - logZ;
#pragma unroll
  for (int off = 32; off; off >>= 1) contrib += __shfl_xor(contrib, off, 64);
  if (lane == 0) atomicAdd(loss, -contrib);
}

__global__ void finalize_kernel(const float* __restrict__ loss, void* __restrict__ out,
                                const int* __restrict__ flag)
{
  float v = loss[0] * (1.f / BT);
  if (flag[0]) ((float*)out)[(size_t)BT * VV] = v;
  else         ((bf16*)out)[(size_t)BT * VV]  = f2b(v);
}

// ---------------------------------------------------------------------------
extern "C" void kernel_launch(void* const* d_in, const int* in_sizes, int n_in,
                              void* d_out, int out_size, void* d_ws, size_t ws_size,
                              hipStream_t stream)
{
  const int* idx     = (const int*)d_in[0];
  const int* targets = (const int*)d_in[1];
  const void* tok  = d_in[2];
  const void* pos  = d_in[3];
  const void* Wq   = d_in[4];
  const void* Wk   = d_in[5];
  const void* Wv   = d_in[6];
  const void* Wo   = d_in[7];
  const void* bo   = d_in[8];
  const void* W1   = d_in[9];
  const void* b1   = d_in[10];
  const void* W2   = d_in[11];
  const void* b2   = d_in[12];
  const void* ln1g = d_in[13];
  const void* ln1b = d_in[14];
  const void* ln2g = d_in[15];
  const void* ln2b = d_in[16];
  const void* lnfg = d_in[17];
  const void* lnfb = d_in[18];
  const void* Wlm  = d_in[19];
  const void* blm  = d_in[20];

  char* ws = (char*)d_ws;
  size_t off = 0;
  auto alloc = [&](size_t bytes) { void* p = ws + off; off += (bytes + 255) & ~(size_t)255; return p; };

  float* x   = (float*)alloc((size_t)BT * CC * 4);            // 50.3 MB
  bf16*  xn  = (bf16*)alloc((size_t)BT * CC * 2);             // 25.2 MB
  bf16*  qb  = (bf16*)alloc((size_t)BB * HH * TT * DH * 2);   // 16.8 MB x3 (contiguous)
  bf16*  kb  = (bf16*)alloc((size_t)BB * HH * TT * DH * 2);
  bf16*  vb  = (bf16*)alloc((size_t)BB * HH * TT * DH * 2);
  bf16*  att = (bf16*)alloc((size_t)BT * 256 * 2);            // 16.8 MB
  bf16*  ff1 = qb;   // FF phase aliases dead q/k/v buffers (FCH*FFD*2 = 50.33MB = qkv exactly)
  // canonical bf16 weights
  bf16* c_tok  = (bf16*)alloc((size_t)VV * CC * 2);
  bf16* c_pos  = (bf16*)alloc((size_t)TT * CC * 2);
  bf16* wqkvT  = (bf16*)alloc((size_t)LL * 768 * CC * 2);     // B^T for fused QKV
  bf16* woT    = (bf16*)alloc((size_t)LL * CC * 256 * 2);     // B^T [C][256]
  bf16* w1T    = (bf16*)alloc((size_t)LL * FFD * CC * 2);     // B^T [FFD][C]
  bf16* w2T    = (bf16*)alloc((size_t)LL * CC * FFD * 2);     // B^T [C][FFD]
  bf16* c_bo   = (bf16*)alloc((size_t)LL * CC * 2);
  bf16* c_b1   = (bf16*)alloc((size_t)LL * FFD * 2);
  bf16* c_b2   = (bf16*)alloc((size_t)LL * CC * 2);
  bf16* c_l1g  = (bf16*)alloc((size_t)LL * CC * 2);
  bf16* c_l1b  = (bf16*)alloc((size_t)LL * CC * 2);
  bf16* c_l2g  = (bf16*)alloc((size_t)LL * CC * 2);
  bf16* c_l2b  = (bf16*)alloc((size_t)LL * CC * 2);
  bf16* c_lfg  = (bf16*)alloc((size_t)CC * 2);
  bf16* c_lfb  = (bf16*)alloc((size_t)CC * 2);
  bf16* c_Wlm  = (bf16*)alloc((size_t)CC * VV * 2);
  bf16* c_blm  = (bf16*)alloc((size_t)VV * 2);
  float* loss  = (float*)alloc(256);
  int*   flag  = (int*)alloc(256);

  hipMemsetAsync(loss, 0, 4, stream);

  detect_kernel<<<1, 256, 0, stream>>>((const unsigned short*)tok, flag);

  auto conv = [&](const void* src, bf16* dst, int n) {
    convert_kernel<<<(n + 255) / 256, 256, 0, stream>>>(src, dst, n, flag);
  };
  conv(tok,  c_tok, VV * CC);
  conv(pos,  c_pos, TT * CC);
  conv(bo,   c_bo,  LL * CC);
  conv(b1,   c_b1,  LL * FFD);
  conv(b2,   c_b2,  LL * CC);
  conv(ln1g, c_l1g, LL * CC);
  conv(ln1b, c_l1b, LL * CC);
  conv(ln2g, c_l2g, LL * CC);
  conv(ln2b, c_l2b, LL * CC);
  conv(lnfg, c_lfg, CC);
  conv(lnfb, c_lfb, CC);
  conv(Wlm,  c_Wlm, CC * VV);
  conv(blm,  c_blm, VV);

  {
    int tq = LL * 768 * CC;
    repack_qkvT<<<(tq + 255) / 256, 256, 0, stream>>>(Wq, Wk, Wv, wqkvT, flag);
    int t1 = LL * 256 * CC;
    transpose_w<<<(t1 + 255) / 256, 256, 0, stream>>>(Wo, woT, 256, CC, t1, flag);
    int t2 = LL * CC * FFD;
    transpose_w<<<(t2 + 255) / 256, 256, 0, stream>>>(W1, w1T, CC, FFD, t2, flag);
    transpose_w<<<(t2 + 255) / 256, 256, 0, stream>>>(W2, w2T, FFD, CC, t2, flag);
  }

  embed_kernel<<<BT, CC, 0, stream>>>(idx, c_tok, c_pos, x);

  for (int l = 0; l < LL; ++l) {
    ln_kernel<<<BT / 4, 256, 0, stream>>>(x, xn, c_l1g + l * CC, c_l1b + l * CC);

    // fused QKV: [BT,768] = xn[BT,384] * WqkvT^T ; scatter to qb/kb/vb
    mfma_gemm<OUT_QKV, false><<<dim3(768 / 128, BT / 128), 256, 0, stream>>>(
        xn, wqkvT + (size_t)l * 768 * CC, nullptr, qb, BT, 768, CC);

    attn_mfma_kernel<<<BB * HH, 512, 0, stream>>>(qb, kb, vb, att);

    mfma_gemm<OUT_RES, false><<<dim3(CC / 128, BT / 128), 256, 0, stream>>>(
        att, woT + (size_t)l * CC * 256, c_bo + l * CC, x, BT, CC, 256);

    ln_kernel<<<BT / 4, 256, 0, stream>>>(x, xn, c_l2g + l * CC, c_l2b + l * CC);

    for (int ch = 0; ch < BT / FCH; ++ch) {
      const bf16* Ach = xn + (size_t)ch * FCH * CC;
      mfma_gemm<OUT_BF16, true><<<dim3(FFD / 128, FCH / 128), 256, 0, stream>>>(
          Ach, w1T + (size_t)l * FFD * CC, c_b1 + l * FFD, ff1, FCH, FFD, CC);
      mfma_gemm<OUT_RES, false><<<dim3(CC / 128, FCH / 128), 256, 0, stream>>>(
          ff1, w2T + (size_t)l * CC * FFD, c_b2 + l * CC, x + (size_t)ch * FCH * CC, FCH, CC, FFD);
    }
  }

  ln_kernel<<<BT / 4, 256, 0, stream>>>(x, xn, c_lfg, c_lfb);
  lmhead_kernel<<<BT, 64, 0, stream>>>(xn, c_Wlm, c_blm, targets, d_out, loss, flag);
  finalize_kernel<<<1, 1, 0, stream>>>(loss, d_out, flag);
}

// Round 5
// 2322.603 us; speedup vs baseline: 9.5537x; 1.0471x over previous
//
#include <hip/hip_runtime.h>
#include <hip/hip_bf16.h>

typedef __hip_bfloat16 bf16;

// Problem constants
#define BB   128
#define TT   256
#define CC   384
#define HH   4
#define DH   64
#define LL   6
#define VV   65
#define FFD  1536
#define BT   (BB * TT)   // 32768
#define FCH  16384       // FF row-chunk (2 chunks)

__device__ __forceinline__ float b2f(bf16 h) { return __bfloat162float(h); }
__device__ __forceinline__ bf16  f2b(float f) { return __float2bfloat16(f); }

typedef __bf16 bf16x8 __attribute__((ext_vector_type(8)));
typedef float  f32x4  __attribute__((ext_vector_type(4)));

__device__ __forceinline__ __bf16 f2n(float f) {
  bf16 h = f2b(f);
  return __builtin_bit_cast(__bf16, h);
}

// global(16B) -> LDS direct copy; LDS dest = wave-uniform base + lane*16
__device__ __forceinline__ void gld_lds16(const void* g, void* l) {
  __builtin_amdgcn_global_load_lds(
      (const __attribute__((address_space(1))) unsigned int*)(unsigned long long)g,
      (__attribute__((address_space(3))) unsigned int*)(unsigned long long)l,
      16, 0, 0);
}

// ---------------------------------------------------------------------------
// Detect input dtype: fp32 (flag=1) vs bf16 (flag=0), via tok_emb bit patterns.
// ---------------------------------------------------------------------------
__global__ __launch_bounds__(256) void detect_kernel(const unsigned short* __restrict__ tok,
                                                     int* __restrict__ flag)
{
  __shared__ int cnt;
  if (threadIdx.x == 0) cnt = 0;
  __syncthreads();
  int c = 0;
  for (int i = threadIdx.x; i < 512; i += 256) {
    int e = (tok[i] >> 7) & 0xFF;
    if (e >= 130) c++;
  }
  atomicAdd(&cnt, c);
  __syncthreads();
  if (threadIdx.x == 0) flag[0] = (cnt > 16) ? 1 : 0;
}

__device__ __forceinline__ float load_flag(const void* src, size_t i, int fl) {
  return fl ? ((const float*)src)[i] : b2f(((const bf16*)src)[i]);
}

// Canonicalize a float tensor (fp32 or bf16 per flag) into bf16.
__global__ __launch_bounds__(256) void convert_kernel(const void* __restrict__ src,
                                                      bf16* __restrict__ dst, int n,
                                                      const int* __restrict__ flag)
{
  int i = blockIdx.x * 256 + threadIdx.x;
  if (i >= n) return;
  dst[i] = f2b(load_flag(src, i, flag[0]));
}

// Generic per-layer transpose: in [L][R][Cc] -> out [L][Cc][R] (bf16), coalesced out.
__global__ __launch_bounds__(256) void transpose_w(const void* __restrict__ src,
                                                   bf16* __restrict__ dst,
                                                   int R, int Cc, int total,
                                                   const int* __restrict__ flag)
{
  int o = blockIdx.x * 256 + threadIdx.x;
  if (o >= total) return;
  int i2 = o % R;
  int j  = (o / R) % Cc;
  int l  = o / (R * Cc);
  dst[o] = f2b(load_flag(src, ((size_t)(l * R + i2)) * Cc + j, flag[0]));
}

// Wlm^T padded repack: dst[n][c] (n<128) = Wlm[c][n] for n<65 else 0.
__global__ __launch_bounds__(256) void repack_lmT(const void* __restrict__ wlm,
                                                  bf16* __restrict__ dst,
                                                  const int* __restrict__ flag)
{
  int o = blockIdx.x * 256 + threadIdx.x;   // total = 128*CC
  if (o >= 128 * CC) return;
  int c = o % CC;
  int n = o / CC;
  float v = (n < VV) ? load_flag(wlm, (size_t)c * VV + n, flag[0]) : 0.f;
  dst[o] = f2b(v);
}

// Fused QKV B^T repack: dst[l][n][c] (n in 0..767) from Wq/Wk/Wv [L,H,C,HS].
__global__ __launch_bounds__(256) void repack_qkvT(const void* __restrict__ wq,
                                                   const void* __restrict__ wk,
                                                   const void* __restrict__ wv,
                                                   bf16* __restrict__ dst,
                                                   const int* __restrict__ flag)
{
  int o = blockIdx.x * 256 + threadIdx.x;   // total = LL*768*CC
  if (o >= LL * 768 * CC) return;
  int c = o % CC;
  int n = (o / CC) % 768;
  int l = o / (CC * 768);
  const void* src = (n < 256) ? wq : (n < 512) ? wk : wv;
  int h = (n >> 6) & 3, d = n & 63;
  dst[o] = f2b(load_flag(src, (((size_t)(l * HH + h)) * CC + c) * DH + d, flag[0]));
}

// ---------------------------------------------------------------------------
// Embedding: x[bt, c] = tok_emb[idx[bt], c] + pos_emb[bt % T, c]   (fp32 out)
// ---------------------------------------------------------------------------
__global__ __launch_bounds__(CC) void embed_kernel(
    const int* __restrict__ idx, const bf16* __restrict__ tok,
    const bf16* __restrict__ pos, float* __restrict__ x)
{
  int bt = blockIdx.x;
  int c  = threadIdx.x;
  int tok_id = idx[bt];
  int t = bt & (TT - 1);
  x[(size_t)bt * CC + c] = b2f(tok[(size_t)tok_id * CC + c]) + b2f(pos[(size_t)t * CC + c]);
}

// ---------------------------------------------------------------------------
// LayerNorm: fp32 x row -> bf16 xn row. One wave per row (C=384 -> 6/lane).
// ---------------------------------------------------------------------------
__global__ __launch_bounds__(256) void ln_kernel(
    const float* __restrict__ x, bf16* __restrict__ xn,
    const bf16* __restrict__ g, const bf16* __restrict__ b)
{
  int lane = threadIdx.x & 63;
  int wid  = threadIdx.x >> 6;
  int r = blockIdx.x * 4 + wid;
  const float* xr = x + (size_t)r * CC;
  float vals[6];
  float s = 0.f, ss = 0.f;
#pragma unroll
  for (int i = 0; i < 6; ++i) {
    float v = xr[lane + i * 64];
    vals[i] = v; s += v; ss += v * v;
  }
#pragma unroll
  for (int off = 32; off; off >>= 1) {
    s  += __shfl_xor(s, off, 64);
    ss += __shfl_xor(ss, off, 64);
  }
  float mu   = s * (1.f / CC);
  float var  = ss * (1.f / CC) - mu * mu;
  float rstd = rsqrtf(var + 1e-5f);
  bf16* xo = xn + (size_t)r * CC;
#pragma unroll
  for (int i = 0; i < 6; ++i) {
    int c = lane + i * 64;
    xo[c] = f2b((vals[i] - mu) * rstd * b2f(g[c]) + b2f(b[c]));
  }
}

// ---------------------------------------------------------------------------
// MFMA GEMM: C[M,N] = A[M,K](bf16,row-major) * B(given as B^T [N,K] bf16).
// 128x128 tile, BK=64, 4 waves, 16x16x32 bf16 MFMA, fp32 acc.
// ---------------------------------------------------------------------------
enum { OUT_BF16 = 0, OUT_QKV = 1, OUT_RES = 2, OUT_LMH = 3 };

template<int MODE, bool RELU>
__global__ __launch_bounds__(256) void mfma_gemm(
    const bf16* __restrict__ A, const bf16* __restrict__ Bt,
    const bf16* __restrict__ bias, void* __restrict__ out,
    int M, int N, int K)
{
  __shared__ bf16 As[128 * 64];
  __shared__ bf16 Bs[128 * 64];
  const int tid  = threadIdx.x;
  const int w    = tid >> 6, lane = tid & 63;
  const int m0   = blockIdx.y * 128, n0 = blockIdx.x * 128;
  const int wr   = (w >> 1) * 64, wc = (w & 1) * 64;   // wave's 64x64 origin
  const int lrow = lane & 15, lk = lane >> 4;

  f32x4 acc[4][4] = {};

  const int srow8 = lane >> 3;          // 0..7
  const int sup   = lane & 7;           // physical 16B unit

  for (int k0 = 0; k0 < K; k0 += 64) {
#pragma unroll
    for (int i = 0; i < 4; ++i) {
      int row  = w * 32 + i * 8 + srow8;
      int ulog = sup ^ (row & 7);       // pre-swizzled global source unit
      gld_lds16(A  + (size_t)(m0 + row) * K + k0 + ulog * 8, &As[(w * 32 + i * 8) * 64]);
      gld_lds16(Bt + (size_t)(n0 + row) * K + k0 + ulog * 8, &Bs[(w * 32 + i * 8) * 64]);
    }
    __syncthreads();
#pragma unroll
    for (int kk = 0; kk < 2; ++kk) {
      bf16x8 af[4], bg[4];
#pragma unroll
      for (int mi = 0; mi < 4; ++mi) {
        int r = wr + mi * 16 + lrow;
        int u = (kk * 4 + lk) ^ (r & 7);  // swizzled read
        af[mi] = *reinterpret_cast<const bf16x8*>(&As[r * 64 + u * 8]);
      }
#pragma unroll
      for (int ni = 0; ni < 4; ++ni) {
        int r = wc + ni * 16 + lrow;
        int u = (kk * 4 + lk) ^ (r & 7);
        bg[ni] = *reinterpret_cast<const bf16x8*>(&Bs[r * 64 + u * 8]);
      }
#pragma unroll
      for (int mi = 0; mi < 4; ++mi)
#pragma unroll
        for (int ni = 0; ni < 4; ++ni)
          acc[mi][ni] = __builtin_amdgcn_mfma_f32_16x16x32_bf16(af[mi], bg[ni], acc[mi][ni], 0, 0, 0);
    }
    __syncthreads();
  }

  // Epilogue. D layout: col = lane&15, row = (lane>>4)*4 + r
#pragma unroll
  for (int mi = 0; mi < 4; ++mi) {
#pragma unroll
    for (int ni = 0; ni < 4; ++ni) {
#pragma unroll
      for (int r = 0; r < 4; ++r) {
        int m = m0 + wr + mi * 16 + lk * 4 + r;
        int n = n0 + wc + ni * 16 + lrow;
        float v = acc[mi][ni][r];
        if (MODE == OUT_BF16) {
          v += b2f(bias[n]);
          if (RELU) v = fmaxf(v, 0.f);
          reinterpret_cast<bf16*>(out)[(size_t)m * N + n] = f2b(v);
        } else if (MODE == OUT_RES) {
          v += b2f(bias[n]);
          reinterpret_cast<float*>(out)[(size_t)m * N + n] += v;  // fp32 residual
        } else if (MODE == OUT_LMH) {
          if (n < VV)
            reinterpret_cast<float*>(out)[(size_t)m * VV + n] = v + b2f(bias[n]);
        } else {  // OUT_QKV: n<256 q, <512 k, else v; scatter to [B,H,T,DH]
          int which = n >> 8;
          int h = (n >> 6) & 3, d = n & 63;
          int b = m >> 8, trow = m & 255;
          reinterpret_cast<bf16*>(out)[(size_t)which * BB * HH * TT * DH +
              (((size_t)b * HH + h) * TT + trow) * DH + d] = f2b(v);
        }
      }
    }
  }
}

// ---------------------------------------------------------------------------
// MFMA flash attention. One block per (b,h), 512 threads (8 waves).
// ---------------------------------------------------------------------------
__global__ __launch_bounds__(512) void attn_mfma_kernel(
    const bf16* __restrict__ qg, const bf16* __restrict__ kg,
    const bf16* __restrict__ vg, bf16* __restrict__ att)
{
  __shared__ __bf16 stage[128 * 64];        // 16KB: K chunk or Vt chunk
  __shared__ __bf16 Pbuf[8][16 * 128];      // 32KB: per-wave P staging
  const int bh = blockIdx.x;
  const int b  = bh >> 2, h = bh & 3;       // H = 4
  const int tid = threadIdx.x, w = tid >> 6, lane = tid & 63;
  const int l15 = lane & 15, lk = lane >> 4;
  const bf16* Qg = qg + (size_t)bh * TT * DH;
  const bf16* Kg = kg + (size_t)bh * TT * DH;
  const bf16* Vg = vg + (size_t)bh * TT * DH;
  __bf16* Pw = &Pbuf[w][0];

  for (int qp = 0; qp < 2; ++qp) {
    const int qt = qp ? (15 - w) : w;
    const int mrow0 = qt * 16 + lk * 4;

    bf16x8 aq[2];
#pragma unroll
    for (int kk = 0; kk < 2; ++kk)
      aq[kk] = *reinterpret_cast<const bf16x8*>(Qg + (size_t)(qt * 16 + l15) * DH + (kk * 4 + lk) * 8);

    f32x4 sc[16];
#pragma unroll
    for (int ct = 0; ct < 16; ++ct) sc[ct] = (f32x4){0.f, 0.f, 0.f, 0.f};

    // ---- S = Q K^T over two K chunks of 128 rows ----
#pragma unroll
    for (int c = 0; c < 2; ++c) {
      {
        int rl = w * 16;
#pragma unroll
        for (int i = 0; i < 2; ++i) {
          int row  = rl + i * 8 + (lane >> 3);
          int ulog = (lane & 7) ^ (row & 7);
          gld_lds16(Kg + (size_t)(c * 128 + row) * DH + ulog * 8, &stage[(rl + i * 8) * DH]);
        }
      }
      __syncthreads();
#pragma unroll
      for (int ctl = 0; ctl < 8; ++ctl) {
        int srow = ctl * 16 + l15;
        int ct = c * 8 + ctl;
#pragma unroll
        for (int kk = 0; kk < 2; ++kk) {
          bf16x8 kf = *reinterpret_cast<const bf16x8*>(
              &stage[srow * DH + (((kk * 4 + lk) ^ (srow & 7)) * 8)]);
          sc[ct] = __builtin_amdgcn_mfma_f32_16x16x32_bf16(aq[kk], kf, sc[ct], 0, 0, 0);
        }
      }
      __syncthreads();
    }

    // ---- softmax (registers only) ----
    float mr[4] = {-1e30f, -1e30f, -1e30f, -1e30f};
#pragma unroll
    for (int ct = 0; ct < 16; ++ct) {
      int s = ct * 16 + l15;
#pragma unroll
      for (int r = 0; r < 4; ++r) {
        float v = sc[ct][r] * 0.125f;
        if (s > mrow0 + r) v = -1e30f;
        sc[ct][r] = v;
        mr[r] = fmaxf(mr[r], v);
      }
    }
#pragma unroll
    for (int off = 8; off; off >>= 1)
#pragma unroll
      for (int r = 0; r < 4; ++r) mr[r] = fmaxf(mr[r], __shfl_xor(mr[r], off, 64));
    float dsum[4] = {0.f, 0.f, 0.f, 0.f};
#pragma unroll
    for (int ct = 0; ct < 16; ++ct)
#pragma unroll
      for (int r = 0; r < 4; ++r) {
        float e = __expf(sc[ct][r] - mr[r]);
        sc[ct][r] = e;
        dsum[r] += e;
      }
#pragma unroll
    for (int off = 8; off; off >>= 1)
#pragma unroll
      for (int r = 0; r < 4; ++r) dsum[r] += __shfl_xor(dsum[r], off, 64);
    float rd[4];
#pragma unroll
    for (int r = 0; r < 4; ++r) rd[r] = 1.f / dsum[r];

    // ---- O = P V over two V chunks of 128 keys ----
    f32x4 o[4];
#pragma unroll
    for (int nt = 0; nt < 4; ++nt) o[nt] = (f32x4){0.f, 0.f, 0.f, 0.f};

#pragma unroll
    for (int c = 0; c < 2; ++c) {
      {
        int d0 = w * 8;
#pragma unroll
        for (int it = 0; it < 2; ++it) {
          int sl = it * 64 + lane;
          bf16x8 vv = *reinterpret_cast<const bf16x8*>(Vg + (size_t)(c * 128 + sl) * DH + d0);
#pragma unroll
          for (int j = 0; j < 8; ++j) {
            int u = (sl >> 3) ^ j;
            stage[(d0 + j) * 128 + u * 8 + (sl & 7)] = vv[j];
          }
        }
      }
      __syncthreads();
#pragma unroll
      for (int ctl = 0; ctl < 8; ++ctl) {
        int sl = ctl * 16 + l15;
        int u  = sl >> 3;
#pragma unroll
        for (int r = 0; r < 4; ++r) {
          int row = lk * 4 + r;
          Pw[row * 128 + ((u ^ (row & 7)) * 8) + (sl & 7)] = f2n(sc[c * 8 + ctl][r]);
        }
      }
#pragma unroll
      for (int ks = 0; ks < 4; ++ks) {
        bf16x8 pf = *reinterpret_cast<const bf16x8*>(
            &Pw[l15 * 128 + (((ks * 4 + lk) ^ (l15 & 7)) * 8)]);
#pragma unroll
        for (int nt = 0; nt < 4; ++nt) {
          int dd = nt * 16 + l15;
          bf16x8 vf = *reinterpret_cast<const bf16x8*>(
              &stage[dd * 128 + (((ks * 4 + lk) ^ (dd & 7)) * 8)]);
          o[nt] = __builtin_amdgcn_mfma_f32_16x16x32_bf16(pf, vf, o[nt], 0, 0, 0);
        }
      }
      __syncthreads();
    }

#pragma unroll
    for (int nt = 0; nt < 4; ++nt)
#pragma unroll
      for (int r = 0; r < 4; ++r) {
        int t = qt * 16 + lk * 4 + r;
        int d = nt * 16 + l15;
        att[(((size_t)b * TT + t) * HH + h) * DH + d] = f2b(o[nt][r] * rd[r]);
      }
    __syncthreads();
  }
}

// ---------------------------------------------------------------------------
// Loss + d_out write from fp32 logits scratch. One wave per row.
// ---------------------------------------------------------------------------
__global__ __launch_bounds__(256) void loss_kernel(
    const float* __restrict__ logits, const int* __restrict__ targets,
    void* __restrict__ out, float* __restrict__ loss,
    const int* __restrict__ flag)
{
  int wid = threadIdx.x >> 6, lane = threadIdx.x & 63;
  int r = blockIdx.x * 4 + wid;
  const float* lr = logits + (size_t)r * VV;
  float a0 = lr[lane];
  float a1 = (lane == 0) ? lr[64] : -1e30f;

  if (flag[0]) {
    float* o = (float*)out;
    o[(size_t)r * VV + lane] = a0;
    if (lane == 0) o[(size_t)r * VV + 64] = a1;
  } else {
    bf16* o = (bf16*)out;
    o[(size_t)r * VV + lane] = f2b(a0);
    if (lane == 0) o[(size_t)r * VV + 64] = f2b(a1);
  }

  float m = fmaxf(a0, a1);
#pragma unroll
  for (int off = 32; off; off >>= 1) m = fmaxf(m, __shfl_xor(m, off, 64));
  float e = __expf(a0 - m) + ((lane == 0) ? __expf(a1 - m) : 0.f);
#pragma unroll
  for (int off = 32; off; off >>= 1) e += __shfl_xor(e, off, 64);
  float logZ = m + logf(e);
  int tgt = targets[r];
  float contrib = (lane == tgt) ? (a0 - logZ) : 0.f;
  if (lane == 0 && tgt == 64) contrib = a1 - logZ;
#pragma unroll
  for (int off = 32; off; off >>= 1) contrib += __shfl_xor(contrib, off, 64);
  if (lane == 0) atomicAdd(loss, -contrib);
}

__global__ void finalize_kernel(const float* __restrict__ loss, void* __restrict__ out,
                                const int* __restrict__ flag)
{
  float v = loss[0] * (1.f / BT);
  if (flag[0]) ((float*)out)[(size_t)BT * VV] = v;
  else         ((bf16*)out)[(size_t)BT * VV]  = f2b(v);
}

// ---------------------------------------------------------------------------
extern "C" void kernel_launch(void* const* d_in, const int* in_sizes, int n_in,
                              void* d_out, int out_size, void* d_ws, size_t ws_size,
                              hipStream_t stream)
{
  const int* idx     = (const int*)d_in[0];
  const int* targets = (const int*)d_in[1];
  const void* tok  = d_in[2];
  const void* pos  = d_in[3];
  const void* Wq   = d_in[4];
  const void* Wk   = d_in[5];
  const void* Wv   = d_in[6];
  const void* Wo   = d_in[7];
  const void* bo   = d_in[8];
  const void* W1   = d_in[9];
  const void* b1   = d_in[10];
  const void* W2   = d_in[11];
  const void* b2   = d_in[12];
  const void* ln1g = d_in[13];
  const void* ln1b = d_in[14];
  const void* ln2g = d_in[15];
  const void* ln2b = d_in[16];
  const void* lnfg = d_in[17];
  const void* lnfb = d_in[18];
  const void* Wlm  = d_in[19];
  const void* blm  = d_in[20];

  char* ws = (char*)d_ws;
  size_t off = 0;
  auto alloc = [&](size_t bytes) { void* p = ws + off; off += (bytes + 255) & ~(size_t)255; return p; };

  float* x   = (float*)alloc((size_t)BT * CC * 4);            // 50.3 MB
  bf16*  xn  = (bf16*)alloc((size_t)BT * CC * 2);             // 25.2 MB
  bf16*  qb  = (bf16*)alloc((size_t)BB * HH * TT * DH * 2);   // 16.8 MB x3 (contiguous)
  bf16*  kb  = (bf16*)alloc((size_t)BB * HH * TT * DH * 2);
  bf16*  vb  = (bf16*)alloc((size_t)BB * HH * TT * DH * 2);
  bf16*  att = (bf16*)alloc((size_t)BT * 256 * 2);            // 16.8 MB
  bf16*  ff1 = qb;    // FF phase aliases dead q/k/v buffers
  float* logits = (float*)att;  // logits scratch aliases dead att (8.5MB <= 16.8MB)
  // canonical bf16 weights
  bf16* c_tok  = (bf16*)alloc((size_t)VV * CC * 2);
  bf16* c_pos  = (bf16*)alloc((size_t)TT * CC * 2);
  bf16* wqkvT  = (bf16*)alloc((size_t)LL * 768 * CC * 2);     // B^T for fused QKV
  bf16* woT    = (bf16*)alloc((size_t)LL * CC * 256 * 2);     // B^T [C][256]
  bf16* w1T    = (bf16*)alloc((size_t)LL * FFD * CC * 2);     // B^T [FFD][C]
  bf16* w2T    = (bf16*)alloc((size_t)LL * CC * FFD * 2);     // B^T [C][FFD]
  bf16* wlmT   = (bf16*)alloc((size_t)128 * CC * 2);          // B^T [128][C], rows>=65 zero
  bf16* c_bo   = (bf16*)alloc((size_t)LL * CC * 2);
  bf16* c_b1   = (bf16*)alloc((size_t)LL * FFD * 2);
  bf16* c_b2   = (bf16*)alloc((size_t)LL * CC * 2);
  bf16* c_l1g  = (bf16*)alloc((size_t)LL * CC * 2);
  bf16* c_l1b  = (bf16*)alloc((size_t)LL * CC * 2);
  bf16* c_l2g  = (bf16*)alloc((size_t)LL * CC * 2);
  bf16* c_l2b  = (bf16*)alloc((size_t)LL * CC * 2);
  bf16* c_lfg  = (bf16*)alloc((size_t)CC * 2);
  bf16* c_lfb  = (bf16*)alloc((size_t)CC * 2);
  bf16* c_blm  = (bf16*)alloc((size_t)VV * 2);
  float* loss  = (float*)alloc(256);
  int*   flag  = (int*)alloc(256);

  hipMemsetAsync(loss, 0, 4, stream);

  detect_kernel<<<1, 256, 0, stream>>>((const unsigned short*)tok, flag);

  auto conv = [&](const void* src, bf16* dst, int n) {
    convert_kernel<<<(n + 255) / 256, 256, 0, stream>>>(src, dst, n, flag);
  };
  conv(tok,  c_tok, VV * CC);
  conv(pos,  c_pos, TT * CC);
  conv(bo,   c_bo,  LL * CC);
  conv(b1,   c_b1,  LL * FFD);
  conv(b2,   c_b2,  LL * CC);
  conv(ln1g, c_l1g, LL * CC);
  conv(ln1b, c_l1b, LL * CC);
  conv(ln2g, c_l2g, LL * CC);
  conv(ln2b, c_l2b, LL * CC);
  conv(lnfg, c_lfg, CC);
  conv(lnfb, c_lfb, CC);
  conv(blm,  c_blm, VV);

  {
    int tq = LL * 768 * CC;
    repack_qkvT<<<(tq + 255) / 256, 256, 0, stream>>>(Wq, Wk, Wv, wqkvT, flag);
    int t1 = LL * 256 * CC;
    transpose_w<<<(t1 + 255) / 256, 256, 0, stream>>>(Wo, woT, 256, CC, t1, flag);
    int t2 = LL * CC * FFD;
    transpose_w<<<(t2 + 255) / 256, 256, 0, stream>>>(W1, w1T, CC, FFD, t2, flag);
    transpose_w<<<(t2 + 255) / 256, 256, 0, stream>>>(W2, w2T, FFD, CC, t2, flag);
    int t3 = 128 * CC;
    repack_lmT<<<(t3 + 255) / 256, 256, 0, stream>>>(Wlm, wlmT, flag);
  }

  embed_kernel<<<BT, CC, 0, stream>>>(idx, c_tok, c_pos, x);

  for (int l = 0; l < LL; ++l) {
    ln_kernel<<<BT / 4, 256, 0, stream>>>(x, xn, c_l1g + l * CC, c_l1b + l * CC);

    mfma_gemm<OUT_QKV, false><<<dim3(768 / 128, BT / 128), 256, 0, stream>>>(
        xn, wqkvT + (size_t)l * 768 * CC, nullptr, qb, BT, 768, CC);

    attn_mfma_kernel<<<BB * HH, 512, 0, stream>>>(qb, kb, vb, att);

    mfma_gemm<OUT_RES, false><<<dim3(CC / 128, BT / 128), 256, 0, stream>>>(
        att, woT + (size_t)l * CC * 256, c_bo + l * CC, x, BT, CC, 256);

    ln_kernel<<<BT / 4, 256, 0, stream>>>(x, xn, c_l2g + l * CC, c_l2b + l * CC);

    for (int ch = 0; ch < BT / FCH; ++ch) {
      const bf16* Ach = xn + (size_t)ch * FCH * CC;
      mfma_gemm<OUT_BF16, true><<<dim3(FFD / 128, FCH / 128), 256, 0, stream>>>(
          Ach, w1T + (size_t)l * FFD * CC, c_b1 + l * FFD, ff1, FCH, FFD, CC);
      mfma_gemm<OUT_RES, false><<<dim3(CC / 128, FCH / 128), 256, 0, stream>>>(
          ff1, w2T + (size_t)l * CC * FFD, c_b2 + l * CC, x + (size_t)ch * FCH * CC, FCH, CC, FFD);
    }
  }

  ln_kernel<<<BT / 4, 256, 0, stream>>>(x, xn, c_lfg, c_lfb);
  // LM head: [BT,384] x [384,65->128] via MFMA, fp32 logits to scratch
  mfma_gemm<OUT_LMH, false><<<dim3(1, BT / 128), 256, 0, stream>>>(
      xn, wlmT, c_blm, logits, BT, 128, CC);
  loss_kernel<<<BT / 4, 256, 0, stream>>>(logits, targets, d_out, loss, flag);
  finalize_kernel<<<1, 1, 0, stream>>>(loss, d_out, flag);
}

// Round 6
// 1938.535 us; speedup vs baseline: 11.4465x; 1.1981x over previous
//
#include <hip/hip_runtime.h>
#include <hip/hip_bf16.h>

typedef __hip_bfloat16 bf16;

// Problem constants
#define BB   128
#define TT   256
#define CC   384
#define HH   4
#define DH   64
#define LL   6
#define VV   65
#define FFD  1536
#define BT   (BB * TT)   // 32768
#define FCH  16384       // FF row-chunk (2 chunks)

__device__ __forceinline__ float b2f(bf16 h) { return __bfloat162float(h); }
__device__ __forceinline__ bf16  f2b(float f) { return __float2bfloat16(f); }

typedef __bf16 bf16x8 __attribute__((ext_vector_type(8)));
typedef float  f32x4  __attribute__((ext_vector_type(4)));

__device__ __forceinline__ __bf16 f2n(float f) {
  bf16 h = f2b(f);
  return __builtin_bit_cast(__bf16, h);
}

// global(16B) -> LDS direct copy; LDS dest = wave-uniform base + lane*16
__device__ __forceinline__ void gld_lds16(const void* g, void* l) {
  __builtin_amdgcn_global_load_lds(
      (const __attribute__((address_space(1))) unsigned int*)(unsigned long long)g,
      (__attribute__((address_space(3))) unsigned int*)(unsigned long long)l,
      16, 0, 0);
}

// ---------------------------------------------------------------------------
// Detect input dtype: fp32 (flag=1) vs bf16 (flag=0), via tok_emb bit patterns.
// ---------------------------------------------------------------------------
__global__ __launch_bounds__(256) void detect_kernel(const unsigned short* __restrict__ tok,
                                                     int* __restrict__ flag)
{
  __shared__ int cnt;
  if (threadIdx.x == 0) cnt = 0;
  __syncthreads();
  int c = 0;
  for (int i = threadIdx.x; i < 512; i += 256) {
    int e = (tok[i] >> 7) & 0xFF;
    if (e >= 130) c++;
  }
  atomicAdd(&cnt, c);
  __syncthreads();
  if (threadIdx.x == 0) flag[0] = (cnt > 16) ? 1 : 0;
}

__device__ __forceinline__ float load_flag(const void* src, size_t i, int fl) {
  return fl ? ((const float*)src)[i] : b2f(((const bf16*)src)[i]);
}

// Canonicalize a float tensor (fp32 or bf16 per flag) into bf16.
__global__ __launch_bounds__(256) void convert_kernel(const void* __restrict__ src,
                                                      bf16* __restrict__ dst, int n,
                                                      const int* __restrict__ flag)
{
  int i = blockIdx.x * 256 + threadIdx.x;
  if (i >= n) return;
  dst[i] = f2b(load_flag(src, i, flag[0]));
}

// Generic per-layer transpose: in [L][R][Cc] -> out [L][Cc][R] (bf16), coalesced out.
__global__ __launch_bounds__(256) void transpose_w(const void* __restrict__ src,
                                                   bf16* __restrict__ dst,
                                                   int R, int Cc, int total,
                                                   const int* __restrict__ flag)
{
  int o = blockIdx.x * 256 + threadIdx.x;
  if (o >= total) return;
  int i2 = o % R;
  int j  = (o / R) % Cc;
  int l  = o / (R * Cc);
  dst[o] = f2b(load_flag(src, ((size_t)(l * R + i2)) * Cc + j, flag[0]));
}

// Wlm^T padded repack: dst[n][c] (n<128) = Wlm[c][n] for n<65 else 0.
__global__ __launch_bounds__(256) void repack_lmT(const void* __restrict__ wlm,
                                                  bf16* __restrict__ dst,
                                                  const int* __restrict__ flag)
{
  int o = blockIdx.x * 256 + threadIdx.x;   // total = 128*CC
  if (o >= 128 * CC) return;
  int c = o % CC;
  int n = o / CC;
  float v = (n < VV) ? load_flag(wlm, (size_t)c * VV + n, flag[0]) : 0.f;
  dst[o] = f2b(v);
}

// Fused QKV B^T repack: dst[l][n][c] (n in 0..767) from Wq/Wk/Wv [L,H,C,HS].
__global__ __launch_bounds__(256) void repack_qkvT(const void* __restrict__ wq,
                                                   const void* __restrict__ wk,
                                                   const void* __restrict__ wv,
                                                   bf16* __restrict__ dst,
                                                   const int* __restrict__ flag)
{
  int o = blockIdx.x * 256 + threadIdx.x;   // total = LL*768*CC
  if (o >= LL * 768 * CC) return;
  int c = o % CC;
  int n = (o / CC) % 768;
  int l = o / (CC * 768);
  const void* src = (n < 256) ? wq : (n < 512) ? wk : wv;
  int h = (n >> 6) & 3, d = n & 63;
  dst[o] = f2b(load_flag(src, (((size_t)(l * HH + h)) * CC + c) * DH + d, flag[0]));
}

// ---------------------------------------------------------------------------
// Embedding: x[bt, c] = tok_emb[idx[bt], c] + pos_emb[bt % T, c]   (fp32 out)
// ---------------------------------------------------------------------------
__global__ __launch_bounds__(CC) void embed_kernel(
    const int* __restrict__ idx, const bf16* __restrict__ tok,
    const bf16* __restrict__ pos, float* __restrict__ x)
{
  int bt = blockIdx.x;
  int c  = threadIdx.x;
  int tok_id = idx[bt];
  int t = bt & (TT - 1);
  x[(size_t)bt * CC + c] = b2f(tok[(size_t)tok_id * CC + c]) + b2f(pos[(size_t)t * CC + c]);
}

// ---------------------------------------------------------------------------
// LayerNorm: fp32 x row -> bf16 xn row. One wave per row (C=384 -> 6/lane).
// ---------------------------------------------------------------------------
__global__ __launch_bounds__(256) void ln_kernel(
    const float* __restrict__ x, bf16* __restrict__ xn,
    const bf16* __restrict__ g, const bf16* __restrict__ b)
{
  int lane = threadIdx.x & 63;
  int wid  = threadIdx.x >> 6;
  int r = blockIdx.x * 4 + wid;
  const float* xr = x + (size_t)r * CC;
  float vals[6];
  float s = 0.f, ss = 0.f;
#pragma unroll
  for (int i = 0; i < 6; ++i) {
    float v = xr[lane + i * 64];
    vals[i] = v; s += v; ss += v * v;
  }
#pragma unroll
  for (int off = 32; off; off >>= 1) {
    s  += __shfl_xor(s, off, 64);
    ss += __shfl_xor(ss, off, 64);
  }
  float mu   = s * (1.f / CC);
  float var  = ss * (1.f / CC) - mu * mu;
  float rstd = rsqrtf(var + 1e-5f);
  bf16* xo = xn + (size_t)r * CC;
#pragma unroll
  for (int i = 0; i < 6; ++i) {
    int c = lane + i * 64;
    xo[c] = f2b((vals[i] - mu) * rstd * b2f(g[c]) + b2f(b[c]));
  }
}

// ---------------------------------------------------------------------------
// MFMA GEMM: C[M,N] = A[M,K](bf16,row-major) * B(given as B^T [N,K] bf16).
// 128x128 tile, BK=64, 4 waves, 16x16x32 bf16 MFMA, fp32 acc.
// ---------------------------------------------------------------------------
enum { OUT_BF16 = 0, OUT_QKV = 1, OUT_RES = 2, OUT_LMH = 3 };

template<int MODE, bool RELU>
__global__ __launch_bounds__(256) void mfma_gemm(
    const bf16* __restrict__ A, const bf16* __restrict__ Bt,
    const bf16* __restrict__ bias, void* __restrict__ out,
    int M, int N, int K)
{
  __shared__ bf16 As[128 * 64];
  __shared__ bf16 Bs[128 * 64];
  const int tid  = threadIdx.x;
  const int w    = tid >> 6, lane = tid & 63;
  const int m0   = blockIdx.y * 128, n0 = blockIdx.x * 128;
  const int wr   = (w >> 1) * 64, wc = (w & 1) * 64;   // wave's 64x64 origin
  const int lrow = lane & 15, lk = lane >> 4;

  f32x4 acc[4][4] = {};

  const int srow8 = lane >> 3;          // 0..7
  const int sup   = lane & 7;           // physical 16B unit

  for (int k0 = 0; k0 < K; k0 += 64) {
#pragma unroll
    for (int i = 0; i < 4; ++i) {
      int row  = w * 32 + i * 8 + srow8;
      int ulog = sup ^ (row & 7);       // pre-swizzled global source unit
      gld_lds16(A  + (size_t)(m0 + row) * K + k0 + ulog * 8, &As[(w * 32 + i * 8) * 64]);
      gld_lds16(Bt + (size_t)(n0 + row) * K + k0 + ulog * 8, &Bs[(w * 32 + i * 8) * 64]);
    }
    __syncthreads();
#pragma unroll
    for (int kk = 0; kk < 2; ++kk) {
      bf16x8 af[4], bg[4];
#pragma unroll
      for (int mi = 0; mi < 4; ++mi) {
        int r = wr + mi * 16 + lrow;
        int u = (kk * 4 + lk) ^ (r & 7);  // swizzled read
        af[mi] = *reinterpret_cast<const bf16x8*>(&As[r * 64 + u * 8]);
      }
#pragma unroll
      for (int ni = 0; ni < 4; ++ni) {
        int r = wc + ni * 16 + lrow;
        int u = (kk * 4 + lk) ^ (r & 7);
        bg[ni] = *reinterpret_cast<const bf16x8*>(&Bs[r * 64 + u * 8]);
      }
#pragma unroll
      for (int mi = 0; mi < 4; ++mi)
#pragma unroll
        for (int ni = 0; ni < 4; ++ni)
          acc[mi][ni] = __builtin_amdgcn_mfma_f32_16x16x32_bf16(af[mi], bg[ni], acc[mi][ni], 0, 0, 0);
    }
    __syncthreads();
  }

  // Epilogue. D layout: col = lane&15, row = (lane>>4)*4 + r
#pragma unroll
  for (int mi = 0; mi < 4; ++mi) {
#pragma unroll
    for (int ni = 0; ni < 4; ++ni) {
#pragma unroll
      for (int r = 0; r < 4; ++r) {
        int m = m0 + wr + mi * 16 + lk * 4 + r;
        int n = n0 + wc + ni * 16 + lrow;
        float v = acc[mi][ni][r];
        if (MODE == OUT_BF16) {
          v += b2f(bias[n]);
          if (RELU) v = fmaxf(v, 0.f);
          reinterpret_cast<bf16*>(out)[(size_t)m * N + n] = f2b(v);
        } else if (MODE == OUT_RES) {
          v += b2f(bias[n]);
          reinterpret_cast<float*>(out)[(size_t)m * N + n] += v;  // fp32 residual
        } else if (MODE == OUT_LMH) {
          if (n < VV)
            reinterpret_cast<float*>(out)[(size_t)m * VV + n] = v + b2f(bias[n]);
        } else {  // OUT_QKV: n<256 q, <512 k, else v; scatter to [B,H,T,DH]
          int which = n >> 8;
          int h = (n >> 6) & 3, d = n & 63;
          int b = m >> 8, trow = m & 255;
          reinterpret_cast<bf16*>(out)[(size_t)which * BB * HH * TT * DH +
              (((size_t)b * HH + h) * TT + trow) * DH + d] = f2b(v);
        }
      }
    }
  }
}

// ---------------------------------------------------------------------------
// MFMA flash attention. One block per (b,h), 512 threads (8 waves).
// ---------------------------------------------------------------------------
__global__ __launch_bounds__(512) void attn_mfma_kernel(
    const bf16* __restrict__ qg, const bf16* __restrict__ kg,
    const bf16* __restrict__ vg, bf16* __restrict__ att)
{
  __shared__ __bf16 stage[128 * 64];        // 16KB: K chunk or Vt chunk
  __shared__ __bf16 Pbuf[8][16 * 128];      // 32KB: per-wave P staging
  const int bh = blockIdx.x;
  const int b  = bh >> 2, h = bh & 3;       // H = 4
  const int tid = threadIdx.x, w = tid >> 6, lane = tid & 63;
  const int l15 = lane & 15, lk = lane >> 4;
  const bf16* Qg = qg + (size_t)bh * TT * DH;
  const bf16* Kg = kg + (size_t)bh * TT * DH;
  const bf16* Vg = vg + (size_t)bh * TT * DH;
  __bf16* Pw = &Pbuf[w][0];

  for (int qp = 0; qp < 2; ++qp) {
    const int qt = qp ? (15 - w) : w;
    const int mrow0 = qt * 16 + lk * 4;

    bf16x8 aq[2];
#pragma unroll
    for (int kk = 0; kk < 2; ++kk)
      aq[kk] = *reinterpret_cast<const bf16x8*>(Qg + (size_t)(qt * 16 + l15) * DH + (kk * 4 + lk) * 8);

    f32x4 sc[16];
#pragma unroll
    for (int ct = 0; ct < 16; ++ct) sc[ct] = (f32x4){0.f, 0.f, 0.f, 0.f};

    // ---- S = Q K^T over two K chunks of 128 rows ----
#pragma unroll
    for (int c = 0; c < 2; ++c) {
      {
        int rl = w * 16;
#pragma unroll
        for (int i = 0; i < 2; ++i) {
          int row  = rl + i * 8 + (lane >> 3);
          int ulog = (lane & 7) ^ (row & 7);
          gld_lds16(Kg + (size_t)(c * 128 + row) * DH + ulog * 8, &stage[(rl + i * 8) * DH]);
        }
      }
      __syncthreads();
#pragma unroll
      for (int ctl = 0; ctl < 8; ++ctl) {
        int srow = ctl * 16 + l15;
        int ct = c * 8 + ctl;
#pragma unroll
        for (int kk = 0; kk < 2; ++kk) {
          bf16x8 kf = *reinterpret_cast<const bf16x8*>(
              &stage[srow * DH + (((kk * 4 + lk) ^ (srow & 7)) * 8)]);
          sc[ct] = __builtin_amdgcn_mfma_f32_16x16x32_bf16(aq[kk], kf, sc[ct], 0, 0, 0);
        }
      }
      __syncthreads();
    }

    // ---- softmax (registers only) ----
    float mr[4] = {-1e30f, -1e30f, -1e30f, -1e30f};
#pragma unroll
    for (int ct = 0; ct < 16; ++ct) {
      int s = ct * 16 + l15;
#pragma unroll
      for (int r = 0; r < 4; ++r) {
        float v = sc[ct][r] * 0.125f;
        if (s > mrow0 + r) v = -1e30f;
        sc[ct][r] = v;
        mr[r] = fmaxf(mr[r], v);
      }
    }
#pragma unroll
    for (int off = 8; off; off >>= 1)
#pragma unroll
      for (int r = 0; r < 4; ++r) mr[r] = fmaxf(mr[r], __shfl_xor(mr[r], off, 64));
    float dsum[4] = {0.f, 0.f, 0.f, 0.f};
#pragma unroll
    for (int ct = 0; ct < 16; ++ct)
#pragma unroll
      for (int r = 0; r < 4; ++r) {
        float e = __expf(sc[ct][r] - mr[r]);
        sc[ct][r] = e;
        dsum[r] += e;
      }
#pragma unroll
    for (int off = 8; off; off >>= 1)
#pragma unroll
      for (int r = 0; r < 4; ++r) dsum[r] += __shfl_xor(dsum[r], off, 64);
    float rd[4];
#pragma unroll
    for (int r = 0; r < 4; ++r) rd[r] = 1.f / dsum[r];

    // ---- O = P V over two V chunks of 128 keys ----
    f32x4 o[4];
#pragma unroll
    for (int nt = 0; nt < 4; ++nt) o[nt] = (f32x4){0.f, 0.f, 0.f, 0.f};

#pragma unroll
    for (int c = 0; c < 2; ++c) {
      {
        int d0 = w * 8;
#pragma unroll
        for (int it = 0; it < 2; ++it) {
          int sl = it * 64 + lane;
          bf16x8 vv = *reinterpret_cast<const bf16x8*>(Vg + (size_t)(c * 128 + sl) * DH + d0);
#pragma unroll
          for (int j = 0; j < 8; ++j) {
            int u = (sl >> 3) ^ j;
            stage[(d0 + j) * 128 + u * 8 + (sl & 7)] = vv[j];
          }
        }
      }
      __syncthreads();
#pragma unroll
      for (int ctl = 0; ctl < 8; ++ctl) {
        int sl = ctl * 16 + l15;
        int u  = sl >> 3;
#pragma unroll
        for (int r = 0; r < 4; ++r) {
          int row = lk * 4 + r;
          Pw[row * 128 + ((u ^ (row & 7)) * 8) + (sl & 7)] = f2n(sc[c * 8 + ctl][r]);
        }
      }
#pragma unroll
      for (int ks = 0; ks < 4; ++ks) {
        bf16x8 pf = *reinterpret_cast<const bf16x8*>(
            &Pw[l15 * 128 + (((ks * 4 + lk) ^ (l15 & 7)) * 8)]);
#pragma unroll
        for (int nt = 0; nt < 4; ++nt) {
          int dd = nt * 16 + l15;
          bf16x8 vf = *reinterpret_cast<const bf16x8*>(
              &stage[dd * 128 + (((ks * 4 + lk) ^ (dd & 7)) * 8)]);
          o[nt] = __builtin_amdgcn_mfma_f32_16x16x32_bf16(pf, vf, o[nt], 0, 0, 0);
        }
      }
      __syncthreads();
    }

#pragma unroll
    for (int nt = 0; nt < 4; ++nt)
#pragma unroll
      for (int r = 0; r < 4; ++r) {
        int t = qt * 16 + lk * 4 + r;
        int d = nt * 16 + l15;
        att[(((size_t)b * TT + t) * HH + h) * DH + d] = f2b(o[nt][r] * rd[r]);
      }
    __syncthreads();
  }
}

// ---------------------------------------------------------------------------
// Loss + d_out write from fp32 logits scratch. 256 blocks x 4 waves; each
// wave handles 32 rows; ONE atomic per block (256 total, was 32768).
// ---------------------------------------------------------------------------
__global__ __launch_bounds__(256) void loss_kernel(
    const float* __restrict__ logits, const int* __restrict__ targets,
    void* __restrict__ out, float* __restrict__ loss,
    const int* __restrict__ flag)
{
  __shared__ float wsums[4];
  int wid = threadIdx.x >> 6, lane = threadIdx.x & 63;
  int fl = flag[0];
  float wacc = 0.f;

  for (int i = 0; i < 32; ++i) {
    int r = (blockIdx.x * 4 + wid) * 32 + i;
    const float* lr = logits + (size_t)r * VV;
    float a0 = lr[lane];
    float a1 = (lane == 0) ? lr[64] : -1e30f;

    if (fl) {
      float* o = (float*)out;
      o[(size_t)r * VV + lane] = a0;
      if (lane == 0) o[(size_t)r * VV + 64] = a1;
    } else {
      bf16* o = (bf16*)out;
      o[(size_t)r * VV + lane] = f2b(a0);
      if (lane == 0) o[(size_t)r * VV + 64] = f2b(a1);
    }

    float m = fmaxf(a0, a1);
#pragma unroll
    for (int off = 32; off; off >>= 1) m = fmaxf(m, __shfl_xor(m, off, 64));
    float e = __expf(a0 - m) + ((lane == 0) ? __expf(a1 - m) : 0.f);
#pragma unroll
    for (int off = 32; off; off >>= 1) e += __shfl_xor(e, off, 64);
    float logZ = m + logf(e);
    int tgt = targets[r];
    float contrib = (lane == tgt) ? (a0 - logZ) : 0.f;
    if (lane == 0 && tgt == 64) contrib = a1 - logZ;
#pragma unroll
    for (int off = 32; off; off >>= 1) contrib += __shfl_xor(contrib, off, 64);
    wacc += contrib;
  }

  if (lane == 0) wsums[wid] = wacc;
  __syncthreads();
  if (threadIdx.x == 0)
    atomicAdd(loss, -(wsums[0] + wsums[1] + wsums[2] + wsums[3]));
}

__global__ void finalize_kernel(const float* __restrict__ loss, void* __restrict__ out,
                                const int* __restrict__ flag)
{
  float v = loss[0] * (1.f / BT);
  if (flag[0]) ((float*)out)[(size_t)BT * VV] = v;
  else         ((bf16*)out)[(size_t)BT * VV]  = f2b(v);
}

// ---------------------------------------------------------------------------
extern "C" void kernel_launch(void* const* d_in, const int* in_sizes, int n_in,
                              void* d_out, int out_size, void* d_ws, size_t ws_size,
                              hipStream_t stream)
{
  const int* idx     = (const int*)d_in[0];
  const int* targets = (const int*)d_in[1];
  const void* tok  = d_in[2];
  const void* pos  = d_in[3];
  const void* Wq   = d_in[4];
  const void* Wk   = d_in[5];
  const void* Wv   = d_in[6];
  const void* Wo   = d_in[7];
  const void* bo   = d_in[8];
  const void* W1   = d_in[9];
  const void* b1   = d_in[10];
  const void* W2   = d_in[11];
  const void* b2   = d_in[12];
  const void* ln1g = d_in[13];
  const void* ln1b = d_in[14];
  const void* ln2g = d_in[15];
  const void* ln2b = d_in[16];
  const void* lnfg = d_in[17];
  const void* lnfb = d_in[18];
  const void* Wlm  = d_in[19];
  const void* blm  = d_in[20];

  char* ws = (char*)d_ws;
  size_t off = 0;
  auto alloc = [&](size_t bytes) { void* p = ws + off; off += (bytes + 255) & ~(size_t)255; return p; };

  float* x   = (float*)alloc((size_t)BT * CC * 4);            // 50.3 MB
  bf16*  xn  = (bf16*)alloc((size_t)BT * CC * 2);             // 25.2 MB
  bf16*  qb  = (bf16*)alloc((size_t)BB * HH * TT * DH * 2);   // 16.8 MB x3 (contiguous)
  bf16*  kb  = (bf16*)alloc((size_t)BB * HH * TT * DH * 2);
  bf16*  vb  = (bf16*)alloc((size_t)BB * HH * TT * DH * 2);
  bf16*  att = (bf16*)alloc((size_t)BT * 256 * 2);            // 16.8 MB
  bf16*  ff1 = qb;    // FF phase aliases dead q/k/v buffers
  float* logits = (float*)att;  // logits scratch aliases dead att (8.5MB <= 16.8MB)
  // canonical bf16 weights
  bf16* c_tok  = (bf16*)alloc((size_t)VV * CC * 2);
  bf16* c_pos  = (bf16*)alloc((size_t)TT * CC * 2);
  bf16* wqkvT  = (bf16*)alloc((size_t)LL * 768 * CC * 2);     // B^T for fused QKV
  bf16* woT    = (bf16*)alloc((size_t)LL * CC * 256 * 2);     // B^T [C][256]
  bf16* w1T    = (bf16*)alloc((size_t)LL * FFD * CC * 2);     // B^T [FFD][C]
  bf16* w2T    = (bf16*)alloc((size_t)LL * CC * FFD * 2);     // B^T [C][FFD]
  bf16* wlmT   = (bf16*)alloc((size_t)128 * CC * 2);          // B^T [128][C], rows>=65 zero
  bf16* c_bo   = (bf16*)alloc((size_t)LL * CC * 2);
  bf16* c_b1   = (bf16*)alloc((size_t)LL * FFD * 2);
  bf16* c_b2   = (bf16*)alloc((size_t)LL * CC * 2);
  bf16* c_l1g  = (bf16*)alloc((size_t)LL * CC * 2);
  bf16* c_l1b  = (bf16*)alloc((size_t)LL * CC * 2);
  bf16* c_l2g  = (bf16*)alloc((size_t)LL * CC * 2);
  bf16* c_l2b  = (bf16*)alloc((size_t)LL * CC * 2);
  bf16* c_lfg  = (bf16*)alloc((size_t)CC * 2);
  bf16* c_lfb  = (bf16*)alloc((size_t)CC * 2);
  bf16* c_blm  = (bf16*)alloc((size_t)VV * 2);
  float* loss  = (float*)alloc(256);
  int*   flag  = (int*)alloc(256);

  hipMemsetAsync(loss, 0, 4, stream);

  detect_kernel<<<1, 256, 0, stream>>>((const unsigned short*)tok, flag);

  auto conv = [&](const void* src, bf16* dst, int n) {
    convert_kernel<<<(n + 255) / 256, 256, 0, stream>>>(src, dst, n, flag);
  };
  conv(tok,  c_tok, VV * CC);
  conv(pos,  c_pos, TT * CC);
  conv(bo,   c_bo,  LL * CC);
  conv(b1,   c_b1,  LL * FFD);
  conv(b2,   c_b2,  LL * CC);
  conv(ln1g, c_l1g, LL * CC);
  conv(ln1b, c_l1b, LL * CC);
  conv(ln2g, c_l2g, LL * CC);
  conv(ln2b, c_l2b, LL * CC);
  conv(lnfg, c_lfg, CC);
  conv(lnfb, c_lfb, CC);
  conv(blm,  c_blm, VV);

  {
    int tq = LL * 768 * CC;
    repack_qkvT<<<(tq + 255) / 256, 256, 0, stream>>>(Wq, Wk, Wv, wqkvT, flag);
    int t1 = LL * 256 * CC;
    transpose_w<<<(t1 + 255) / 256, 256, 0, stream>>>(Wo, woT, 256, CC, t1, flag);
    int t2 = LL * CC * FFD;
    transpose_w<<<(t2 + 255) / 256, 256, 0, stream>>>(W1, w1T, CC, FFD, t2, flag);
    transpose_w<<<(t2 + 255) / 256, 256, 0, stream>>>(W2, w2T, FFD, CC, t2, flag);
    int t3 = 128 * CC;
    repack_lmT<<<(t3 + 255) / 256, 256, 0, stream>>>(Wlm, wlmT, flag);
  }

  embed_kernel<<<BT, CC, 0, stream>>>(idx, c_tok, c_pos, x);

  for (int l = 0; l < LL; ++l) {
    ln_kernel<<<BT / 4, 256, 0, stream>>>(x, xn, c_l1g + l * CC, c_l1b + l * CC);

    mfma_gemm<OUT_QKV, false><<<dim3(768 / 128, BT / 128), 256, 0, stream>>>(
        xn, wqkvT + (size_t)l * 768 * CC, nullptr, qb, BT, 768, CC);

    attn_mfma_kernel<<<BB * HH, 512, 0, stream>>>(qb, kb, vb, att);

    mfma_gemm<OUT_RES, false><<<dim3(CC / 128, BT / 128), 256, 0, stream>>>(
        att, woT + (size_t)l * CC * 256, c_bo + l * CC, x, BT, CC, 256);

    ln_kernel<<<BT / 4, 256, 0, stream>>>(x, xn, c_l2g + l * CC, c_l2b + l * CC);

    for (int ch = 0; ch < BT / FCH; ++ch) {
      const bf16* Ach = xn + (size_t)ch * FCH * CC;
      mfma_gemm<OUT_BF16, true><<<dim3(FFD / 128, FCH / 128), 256, 0, stream>>>(
          Ach, w1T + (size_t)l * FFD * CC, c_b1 + l * FFD, ff1, FCH, FFD, CC);
      mfma_gemm<OUT_RES, false><<<dim3(CC / 128, FCH / 128), 256, 0, stream>>>(
          ff1, w2T + (size_t)l * CC * FFD, c_b2 + l * CC, x + (size_t)ch * FCH * CC, FCH, CC, FFD);
    }
  }

  ln_kernel<<<BT / 4, 256, 0, stream>>>(x, xn, c_lfg, c_lfb);
  // LM head: [BT,384] x [384,65->128] via MFMA, fp32 logits to scratch
  mfma_gemm<OUT_LMH, false><<<dim3(1, BT / 128), 256, 0, stream>>>(
      xn, wlmT, c_blm, logits, BT, 128, CC);
  loss_kernel<<<256, 256, 0, stream>>>(logits, targets, d_out, loss, flag);
  finalize_kernel<<<1, 1, 0, stream>>>(loss, d_out, flag);
}